// Round 7
// baseline (993.716 us; speedup 1.0000x reference)
//
#include <hip/hip_runtime.h>
#include <cstdint>
#include <cstddef>

#define B_SZ 8
#define T_LEN 4096
#define HD 1024
#define MTOT (B_SZ * T_LEN)   // 32768 tokens

typedef unsigned short u16;
typedef __attribute__((ext_vector_type(8))) short bf16x8;
typedef __attribute__((ext_vector_type(8))) unsigned short us8;
typedef __attribute__((ext_vector_type(4))) float f32x4;

static __device__ __forceinline__ float bf2f(u16 u) {
    union { unsigned i; float f; } v; v.i = ((unsigned)u) << 16; return v.f;
}
static __device__ __forceinline__ u16 f2bf(float f) {
    union { float f; unsigned i; } v; v.f = f;
    unsigned r = v.i + 0x7fffu + ((v.i >> 16) & 1u);
    return (u16)(r >> 16);
}
static __device__ __forceinline__ float sigm(float x) { return 1.f / (1.f + __expf(-x)); }
static __device__ __forceinline__ float tanh_fast(float x) { return 1.f - 2.f / (1.f + __expf(2.f * x)); }

static __device__ __forceinline__ void gload_lds16(const void* g, void* l) {
    __builtin_amdgcn_global_load_lds((const __attribute__((address_space(1))) void*)g,
                                     (__attribute__((address_space(3))) void*)l, 16, 0, 0);
}

// ---- K0: weights f32 -> bf16: wcat = [v(1024); g(1024); t(1024); r(1024)], wob = Wo
__global__ __launch_bounds__(256) void prep_weights(
    const float* __restrict__ Wp, const float* __restrict__ Wg,
    const float* __restrict__ Wt, const float* __restrict__ Wr,
    const float* __restrict__ Wo, u16* __restrict__ wcat, u16* __restrict__ wob)
{
    int i = blockIdx.x * 256 + threadIdx.x;   // float4 index
    const int T1 = 4096 * 256;
    const int T2 = 1024 * 256;
    if (i < T1) {
        int r = i >> 8, kq = i & 255;
        float4 v;
        if      (r < 1024)  v = ((const float4*)Wp)[(size_t)(r + 1) * 256 + kq];   // v-rows: Wp[1..1024]
        else if (r < 2048)  v = ((const float4*)Wg)[(size_t)(r - 1024) * 256 + kq];
        else if (r < 3072)  v = ((const float4*)Wt)[(size_t)(r - 2048) * 256 + kq];
        else                v = ((const float4*)Wr)[(size_t)(r - 3072) * 256 + kq];
        ushort4 o; o.x = f2bf(v.x); o.y = f2bf(v.y); o.z = f2bf(v.z); o.w = f2bf(v.w);
        ((ushort4*)wcat)[i] = o;
    } else if (i < T1 + T2) {
        int j = i - T1;
        float4 v = ((const float4*)Wo)[j];
        ushort4 o; o.x = f2bf(v.x); o.y = f2bf(v.y); o.z = f2bf(v.z); o.w = f2bf(v.w);
        ((ushort4*)wob)[j] = o;
    }
}

// ---- K1: LayerNorm (f32) -> xn bf16, fused u[m] = xn_f32 . Wp[0] + bp[0] ----
__global__ __launch_bounds__(256) void ln_kernel(
    const float* __restrict__ x, const float* __restrict__ gamma,
    const float* __restrict__ beta, const float* __restrict__ Wp,
    const float* __restrict__ bp, u16* __restrict__ xnb, float* __restrict__ u)
{
    __shared__ float red[8];
    const int row = blockIdx.x, tid = threadIdx.x;
    const float4 v = ((const float4*)(x + (size_t)row * HD))[tid];
    float s  = v.x + v.y + v.z + v.w;
    float sq = v.x * v.x + v.y * v.y + v.z * v.z + v.w * v.w;
    #pragma unroll
    for (int off = 32; off > 0; off >>= 1) {
        s  += __shfl_down(s, off);
        sq += __shfl_down(sq, off);
    }
    if ((tid & 63) == 0) { red[tid >> 6] = s; red[4 + (tid >> 6)] = sq; }
    __syncthreads();
    const float S   = red[0] + red[1] + red[2] + red[3];
    const float SQ  = red[4] + red[5] + red[6] + red[7];
    const float mu  = S * (1.f / HD);
    const float var = SQ * (1.f / HD) - mu * mu;
    const float rs  = rsqrtf(var + 1e-5f);
    const float4 gg = ((const float4*)gamma)[tid];
    const float4 bb = ((const float4*)beta)[tid];
    const float x0 = (v.x - mu) * rs * gg.x + bb.x;
    const float x1 = (v.y - mu) * rs * gg.y + bb.y;
    const float x2 = (v.z - mu) * rs * gg.z + bb.z;
    const float x3 = (v.w - mu) * rs * gg.w + bb.w;
    ushort4 o; o.x = f2bf(x0); o.y = f2bf(x1); o.z = f2bf(x2); o.w = f2bf(x3);
    ((ushort4*)(xnb + (size_t)row * HD))[tid] = o;
    const float4 w0 = ((const float4*)Wp)[tid];
    float su = x0 * w0.x + x1 * w0.y + x2 * w0.z + x3 * w0.w;
    #pragma unroll
    for (int off = 32; off > 0; off >>= 1) su += __shfl_down(su, off);
    __syncthreads();
    if ((tid & 63) == 0) red[tid >> 6] = su;
    __syncthreads();
    if (tid == 0) u[row] = red[0] + red[1] + red[2] + red[3] + bp[0];
}

// ---- K2/K4: bf16 MFMA GEMM, 128x128 tile, BK=64, swizzled LDS.
// Single-barrier pipelined K-loop (T3 minimum 2-phase recipe): per iter
// {vmcnt(0) -> fenced s_barrier -> GSTAGE(next tile) -> ds_read+MFMA(cur)}.
// Stage loads get a full compute phase in flight before their drain.
// NOTE: GSTAGE's internal loop var is jj — rounds 5/6 failed because the
// macro's `j` captured the caller's loop variable (deterministic bad k0).
// 1D XCD-chunked ntile-fast grid.
// MODE 0: swapped-operand MFMA -> transposed tile; epilogue writes bf16 planes
//         Vt/Gt/Tt/Rt laid out [d][MTOT] with 16-lane-contiguous m.
// MODE 1: normal orientation, plain f32 [m][1024] store.
template<int MODE>
__global__ __launch_bounds__(256) void gemm_bt(
    const u16* __restrict__ A, const u16* __restrict__ W, int ntsplit,
    const float* __restrict__ bp,
    u16* __restrict__ Vt, u16* __restrict__ Gt, u16* __restrict__ Tt, u16* __restrict__ Rt,
    float* __restrict__ Cout)
{
    __shared__ u16 sA[2][128 * 64];
    __shared__ u16 sB[2][128 * 64];
    // XCD-chunked bijective remap (gridDim.x % 8 == 0), ntile-fast for A-panel reuse
    const int per = gridDim.x >> 3;
    const int l = (blockIdx.x & 7) * per + (blockIdx.x >> 3);
    const int ntile = l % ntsplit;
    const int mtile = l / ntsplit;

    const int tid = threadIdx.x;
    const int lane = tid & 63, wave = tid >> 6;
    const u16* Ab = A + (size_t)mtile * 128 * 1024;
    const u16* Wb = W + (size_t)ntile * 128 * 1024;

    // staging map: linear LDS chunk q (16B) = row*8 + cl; stored chunk cl holds
    // global chunk cg = cl ^ (row&7)  (inverse-swizzled source, linear dest)
    int offj[4];
    #pragma unroll
    for (int j = 0; j < 4; ++j) {
        const int q = j * 256 + tid;
        const int row = q >> 3;
        const int cg = (q & 7) ^ (row & 7);
        offj[j] = row * 1024 + cg * 8;
    }

    // 8 global_load_lds per thread per stage call (hygienic: jj, no capture)
    #define GSTAGE(bf, k0arg) do {                                               \
        const int k0v_ = (k0arg);                                                \
        _Pragma("unroll")                                                        \
        for (int jj = 0; jj < 4; ++jj) {                                         \
            gload_lds16(Ab + offj[jj] + k0v_, &sA[bf][(jj * 256 + tid) * 8]);    \
            gload_lds16(Wb + offj[jj] + k0v_, &sB[bf][(jj * 256 + tid) * 8]);    \
        }                                                                        \
    } while (0)

    f32x4 acc[4][4] = {};
    const int wm = (wave >> 1) * 64, wn = (wave & 1) * 64;
    const int rA = lane & 15;
    const int clbase = lane & 7;

    GSTAGE(0, 0);                                   // tile 0 -> buf 0
    for (int kt = 0; kt < 16; ++kt) {
        const int p = kt & 1;
        // tile kt (issued last iter or prologue) must be fully in LDS, all waves
        asm volatile("s_waitcnt vmcnt(0)" ::: "memory");
        __builtin_amdgcn_sched_barrier(0);
        __builtin_amdgcn_s_barrier();
        __builtin_amdgcn_sched_barrier(0);
        // prefetch tile kt+1 into buf p^1 (its readers all finished before the
        // barrier above; pinned below the barrier by the sched_barrier fence)
        if (kt < 15) GSTAGE(p ^ 1, (kt + 1) * 64);
        #pragma unroll
        for (int h = 0; h < 2; ++h) {
            const int cl = ((h << 2) + (lane >> 4)) ^ clbase;
            bf16x8 af[4], bfr[4];
            #pragma unroll
            for (int i = 0; i < 4; ++i)
                af[i]  = *(const bf16x8*)(&sA[p][(wm + i * 16 + rA) * 64 + cl * 8]);
            #pragma unroll
            for (int i = 0; i < 4; ++i)
                bfr[i] = *(const bf16x8*)(&sB[p][(wn + i * 16 + rA) * 64 + cl * 8]);
            __builtin_amdgcn_s_setprio(1);
            #pragma unroll
            for (int mi = 0; mi < 4; ++mi)
                #pragma unroll
                for (int ni = 0; ni < 4; ++ni) {
                    if (MODE == 0)   // swapped operands -> D[d][m] (transposed)
                        acc[mi][ni] = __builtin_amdgcn_mfma_f32_16x16x32_bf16(bfr[ni], af[mi], acc[mi][ni], 0, 0, 0);
                    else
                        acc[mi][ni] = __builtin_amdgcn_mfma_f32_16x16x32_bf16(af[mi], bfr[ni], acc[mi][ni], 0, 0, 0);
                }
            __builtin_amdgcn_s_setprio(0);
        }
    }
    #undef GSTAGE

    if (MODE == 1) {
        #pragma unroll
        for (int mi = 0; mi < 4; ++mi) {
            #pragma unroll
            for (int ni = 0; ni < 4; ++ni) {
                const int n = ntile * 128 + wn + ni * 16 + (lane & 15);
                #pragma unroll
                for (int j = 0; j < 4; ++j) {
                    const int m = mtile * 128 + wm + mi * 16 + (lane >> 4) * 4 + j;
                    Cout[(size_t)m * 1024 + n] = acc[mi][ni][j];
                }
            }
        }
    } else {
        const int seg = ntile >> 3;               // 0:V 1:G 2:T 3:R (block-uniform)
        const int dbase = (ntile & 7) * 128 + wn; // plane-d base for this wave
        #pragma unroll
        for (int mi = 0; mi < 4; ++mi) {
            const int m = mtile * 128 + wm + mi * 16 + (lane & 15);
            #pragma unroll
            for (int ni = 0; ni < 4; ++ni) {
                #pragma unroll
                for (int j = 0; j < 4; ++j) {
                    const int d = dbase + ni * 16 + (lane >> 4) * 4 + j;
                    const float val = acc[mi][ni][j];
                    if (seg == 0) {
                        Vt[(size_t)d * MTOT + m] = f2bf(val + bp[1 + d]);
                    } else if (seg == 1) {
                        Gt[(size_t)d * MTOT + m] = f2bf(sigm(val));
                    } else if (seg == 2) {
                        Tt[(size_t)d * MTOT + m] = f2bf(tanh_fast(val));
                    } else {
                        Rt[(size_t)d * MTOT + m] = f2bf(sigm(val));
                    }
                }
            }
        }
    }
}

// ---- K3: LDS-free sequential dual cumsum over transposed planes -------------
__global__ __launch_bounds__(64) void scan_t(
    const u16* __restrict__ Vt, const u16* __restrict__ Gt,
    const u16* __restrict__ Tt, const u16* __restrict__ Rt,
    const float* __restrict__ ub, u16* __restrict__ outb,
    float* __restrict__ act_last, float* __restrict__ gho_last)
{
    const int lane = threadIdx.x;
    const int b  = blockIdx.x >> 4;
    const int d  = ((blockIdx.x & 15) << 6) + lane;
    const int bm0 = b * T_LEN;
    const size_t rbase = (size_t)d * MTOT + bm0;
    const us8* pv = (const us8*)(Vt + rbase);
    const us8* pg = (const us8*)(Gt + rbase);
    const us8* pt = (const us8*)(Tt + rbase);
    const us8* pr = (const us8*)(Rt + rbase);

    us8 cv[2], cg[2], ct_[2], cr[2];
    #pragma unroll
    for (int h = 0; h < 2; ++h) { cv[h] = pv[h]; cg[h] = pg[h]; ct_[h] = pt[h]; cr[h] = pr[h]; }

    float acc_a = 0.f;
    _Float16 acc_g = (_Float16)0.f;

    for (int c = 0; c < 256; ++c) {
        const int cn = (c < 255) ? c + 1 : c;
        us8 nv[2], ng[2], nt2[2], nr[2];
        #pragma unroll
        for (int h = 0; h < 2; ++h) {
            nv[h] = pv[cn * 2 + h]; ng[h] = pg[cn * 2 + h];
            nt2[h] = pt[cn * 2 + h]; nr[h] = pr[cn * 2 + h];
        }
        #pragma unroll
        for (int s = 0; s < 16; ++s) {
            const int h = s >> 3, e = s & 7;
            const int t = c * 16 + s;
            const float v  = bf2f(cv[h][e]);
            const float g  = bf2f(cg[h][e]);
            const float th = bf2f(ct_[h][e]);
            const float r  = bf2f(cr[h][e]);
            const float uu = ub[bm0 + t];                 // uniform -> s_load
            acc_a = fmaf(uu, v, acc_a);                   // f32 sequential cumsum
            acc_g = acc_g + (_Float16)(g * th);           // fp16 RNE sequential cumsum
            const float comb = acc_a + (float)acc_g;
            outb[(size_t)(bm0 + t) * HD + d] = f2bf(r * comb);
        }
        #pragma unroll
        for (int h = 0; h < 2; ++h) { cv[h] = nv[h]; cg[h] = ng[h]; ct_[h] = nt2[h]; cr[h] = nr[h]; }
    }
    act_last[(size_t)b * HD + d] = acc_a;
    gho_last[(size_t)b * HD + d] = (float)acc_g;
}

extern "C" void kernel_launch(void* const* d_in, const int* in_sizes, int n_in,
                              void* d_out, int out_size, void* d_ws, size_t ws_size,
                              hipStream_t stream)
{
    const float* x   = (const float*)d_in[0];
    const float* gam = (const float*)d_in[1];
    const float* bet = (const float*)d_in[2];
    const float* Wp  = (const float*)d_in[3];
    const float* bp  = (const float*)d_in[4];
    const float* Wg  = (const float*)d_in[5];
    const float* Wt  = (const float*)d_in[6];
    const float* Wr  = (const float*)d_in[7];
    const float* Wo  = (const float*)d_in[8];

    float* out0     = (float*)d_out;                       // (B,T,H) f32
    float* act_last = out0 + (size_t)MTOT * HD;            // (B,D) f32
    float* gho_last = act_last + (size_t)B_SZ * HD;        // (B,D) fp16-valued f32

    char* ws = (char*)d_ws;
    const size_t SZ = (size_t)MTOT * HD * 2;               // 64 MiB per bf16 plane
    u16* xnb  = (u16*)(ws);                                // xn bf16; later scan output
    u16* Vt   = (u16*)(ws + SZ);                           // transposed planes [d][MTOT]
    u16* Gt   = (u16*)(ws + 2 * SZ);
    u16* Tt   = (u16*)(ws + 3 * SZ);
    u16* Rt   = (u16*)(ws + 4 * SZ);
    u16* wcat = (u16*)(ws + 5 * SZ);                       // 8,388,608 B
    u16* wob  = (u16*)(ws + 5 * SZ + 8388608);             // 2,097,152 B
    float* ub = (float*)(ws + 5 * SZ + 8388608 + 2097152); // 131,072 B

    prep_weights<<<5120, 256, 0, stream>>>(Wp, Wg, Wt, Wr, Wo, wcat, wob);
    ln_kernel<<<MTOT, 256, 0, stream>>>(x, gam, bet, Wp, bp, xnb, ub);
    gemm_bt<0><<<8192, 256, 0, stream>>>(xnb, wcat, 32, bp, Vt, Gt, Tt, Rt, nullptr);
    scan_t<<<128, 64, 0, stream>>>(Vt, Gt, Tt, Rt, ub, xnb /*out*/, act_last, gho_last);
    gemm_bt<1><<<2048, 256, 0, stream>>>(xnb, wob, 8, bp, nullptr, nullptr, nullptr, nullptr, out0);
}

// Round 8
// 915.208 us; speedup vs baseline: 1.0858x; 1.0858x over previous
//
#include <hip/hip_runtime.h>
#include <cstdint>
#include <cstddef>

#define B_SZ 8
#define T_LEN 4096
#define HD 1024
#define MTOT (B_SZ * T_LEN)   // 32768 tokens

typedef unsigned short u16;
typedef __attribute__((ext_vector_type(8))) short bf16x8;
typedef __attribute__((ext_vector_type(8))) unsigned short us8;
typedef __attribute__((ext_vector_type(4))) float f32x4;

static __device__ __forceinline__ float bf2f(u16 u) {
    union { unsigned i; float f; } v; v.i = ((unsigned)u) << 16; return v.f;
}
static __device__ __forceinline__ u16 f2bf(float f) {
    union { float f; unsigned i; } v; v.f = f;
    unsigned r = v.i + 0x7fffu + ((v.i >> 16) & 1u);
    return (u16)(r >> 16);
}
static __device__ __forceinline__ float sigm(float x) { return 1.f / (1.f + __expf(-x)); }
static __device__ __forceinline__ float tanh_fast(float x) { return 1.f - 2.f / (1.f + __expf(2.f * x)); }

static __device__ __forceinline__ void gload_lds16(const void* g, void* l) {
    __builtin_amdgcn_global_load_lds((const __attribute__((address_space(1))) void*)g,
                                     (__attribute__((address_space(3))) void*)l, 16, 0, 0);
}

// ---- K0: weights f32 -> bf16: wcat = [v(1024); g(1024); t(1024); r(1024)], wob = Wo
__global__ __launch_bounds__(256) void prep_weights(
    const float* __restrict__ Wp, const float* __restrict__ Wg,
    const float* __restrict__ Wt, const float* __restrict__ Wr,
    const float* __restrict__ Wo, u16* __restrict__ wcat, u16* __restrict__ wob)
{
    int i = blockIdx.x * 256 + threadIdx.x;   // float4 index
    const int T1 = 4096 * 256;
    const int T2 = 1024 * 256;
    if (i < T1) {
        int r = i >> 8, kq = i & 255;
        float4 v;
        if      (r < 1024)  v = ((const float4*)Wp)[(size_t)(r + 1) * 256 + kq];   // v-rows: Wp[1..1024]
        else if (r < 2048)  v = ((const float4*)Wg)[(size_t)(r - 1024) * 256 + kq];
        else if (r < 3072)  v = ((const float4*)Wt)[(size_t)(r - 2048) * 256 + kq];
        else                v = ((const float4*)Wr)[(size_t)(r - 3072) * 256 + kq];
        ushort4 o; o.x = f2bf(v.x); o.y = f2bf(v.y); o.z = f2bf(v.z); o.w = f2bf(v.w);
        ((ushort4*)wcat)[i] = o;
    } else if (i < T1 + T2) {
        int j = i - T1;
        float4 v = ((const float4*)Wo)[j];
        ushort4 o; o.x = f2bf(v.x); o.y = f2bf(v.y); o.z = f2bf(v.z); o.w = f2bf(v.w);
        ((ushort4*)wob)[j] = o;
    }
}

// ---- K1: LayerNorm (f32) -> xn bf16, fused u[m] = xn_f32 . Wp[0] + bp[0] ----
__global__ __launch_bounds__(256) void ln_kernel(
    const float* __restrict__ x, const float* __restrict__ gamma,
    const float* __restrict__ beta, const float* __restrict__ Wp,
    const float* __restrict__ bp, u16* __restrict__ xnb, float* __restrict__ u)
{
    __shared__ float red[8];
    const int row = blockIdx.x, tid = threadIdx.x;
    const float4 v = ((const float4*)(x + (size_t)row * HD))[tid];
    float s  = v.x + v.y + v.z + v.w;
    float sq = v.x * v.x + v.y * v.y + v.z * v.z + v.w * v.w;
    #pragma unroll
    for (int off = 32; off > 0; off >>= 1) {
        s  += __shfl_down(s, off);
        sq += __shfl_down(sq, off);
    }
    if ((tid & 63) == 0) { red[tid >> 6] = s; red[4 + (tid >> 6)] = sq; }
    __syncthreads();
    const float S   = red[0] + red[1] + red[2] + red[3];
    const float SQ  = red[4] + red[5] + red[6] + red[7];
    const float mu  = S * (1.f / HD);
    const float var = SQ * (1.f / HD) - mu * mu;
    const float rs  = rsqrtf(var + 1e-5f);
    const float4 gg = ((const float4*)gamma)[tid];
    const float4 bb = ((const float4*)beta)[tid];
    const float x0 = (v.x - mu) * rs * gg.x + bb.x;
    const float x1 = (v.y - mu) * rs * gg.y + bb.y;
    const float x2 = (v.z - mu) * rs * gg.z + bb.z;
    const float x3 = (v.w - mu) * rs * gg.w + bb.w;
    ushort4 o; o.x = f2bf(x0); o.y = f2bf(x1); o.z = f2bf(x2); o.w = f2bf(x3);
    ((ushort4*)(xnb + (size_t)row * HD))[tid] = o;
    const float4 w0 = ((const float4*)Wp)[tid];
    float su = x0 * w0.x + x1 * w0.y + x2 * w0.z + x3 * w0.w;
    #pragma unroll
    for (int off = 32; off > 0; off >>= 1) su += __shfl_down(su, off);
    __syncthreads();
    if ((tid & 63) == 0) red[tid >> 6] = su;
    __syncthreads();
    if (tid == 0) u[row] = red[0] + red[1] + red[2] + red[3] + bp[0];
}

// ---- K2/K4: bf16 MFMA GEMM, 256x256 tile, 8 waves (2M x 4N), BK=32.
// Depth-1 counted pipeline, one barrier per K-slab:
//   { vmcnt(0); fenced s_barrier; issue slab t+1 -> buf p^1; 12 ds_read + 32 MFMA }
// Issue is post-barrier => buf p^1's readers (slab t-1, finished pre-barrier) done.
// Drain is one full compute phase after issue => latency overlapped.
// LDS: slab [256][32] u16, chunk-XOR swizzle cl = cg ^ (r&3); read cl = (lane>>4)^(lane&3).
// MODE 0: swapped-operand MFMA -> transposed; writes bf16 planes [d][MTOT].
// MODE 1: normal orientation, f32 [m][1024] store.
template<int MODE>
__global__ __launch_bounds__(512) void gemm256(
    const u16* __restrict__ A, const u16* __restrict__ W,
    const float* __restrict__ bp,
    u16* __restrict__ Vt, u16* __restrict__ Gt, u16* __restrict__ Tt, u16* __restrict__ Rt,
    float* __restrict__ Cout)
{
    __shared__ u16 sA[2][256 * 32];   // 32 KiB
    __shared__ u16 sB[2][256 * 32];   // 32 KiB
    const int mtile = blockIdx.x, ntile = blockIdx.y;
    const int tid = threadIdx.x;
    const int lane = tid & 63, wave = tid >> 6;
    const int wm = wave >> 2, wn = wave & 3;     // 2M x 4N wave grid
    const u16* Ab = A + (size_t)mtile * 256 * 1024;
    const u16* Wb = W + (size_t)ntile * 256 * 1024;

    // staging: slab = 1024 chunks (16B); thread stages chunks tid and tid+512 of A and B.
    // stored chunk cs holds global chunk cg = cs ^ (r&3) (inverse-swz source, linear dest)
    int goff[2], loff[2];
    #pragma unroll
    for (int jj = 0; jj < 2; ++jj) {
        const int q = jj * 512 + tid;
        const int r = q >> 2;
        goff[jj] = r * 1024 + ((q & 3) ^ (r & 3)) * 8;
        loff[jj] = q * 8;
    }
    auto stage = [&](int pb, int kt) {
        #pragma unroll
        for (int jj = 0; jj < 2; ++jj) {
            gload_lds16(Ab + goff[jj] + kt * 32, &sA[pb][loff[jj]]);
            gload_lds16(Wb + goff[jj] + kt * 32, &sB[pb][loff[jj]]);
        }
    };

    f32x4 acc[8][4] = {};
    const int cl = (lane >> 4) ^ (lane & 3);     // swizzled chunk (r&3 == lane&3: rows are 16-aligned)
    const int aoff = (wm * 128 + (lane & 15)) * 32 + cl * 8;
    const int boff = (wn * 64 + (lane & 15)) * 32 + cl * 8;

    stage(0, 0);
    for (int t = 0; t < 32; ++t) {
        const int p = t & 1;
        asm volatile("s_waitcnt vmcnt(0)" ::: "memory");   // slab t (issued last phase) landed
        __builtin_amdgcn_sched_barrier(0);
        __builtin_amdgcn_s_barrier();                      // all waves' slab-t writes visible
        __builtin_amdgcn_sched_barrier(0);
        if (t < 31) stage(p ^ 1, t + 1);                   // overwrites slab t-1's buffer: readers done pre-barrier
        bf16x8 af[8], bfr[4];
        #pragma unroll
        for (int mi = 0; mi < 8; ++mi)
            af[mi] = *(const bf16x8*)(&sA[p][aoff + mi * 512]);
        #pragma unroll
        for (int ni = 0; ni < 4; ++ni)
            bfr[ni] = *(const bf16x8*)(&sB[p][boff + ni * 512]);
        __builtin_amdgcn_s_setprio(1);
        #pragma unroll
        for (int mi = 0; mi < 8; ++mi)
            #pragma unroll
            for (int ni = 0; ni < 4; ++ni) {
                if (MODE == 0)   // swapped operands -> D[d][m] (transposed)
                    acc[mi][ni] = __builtin_amdgcn_mfma_f32_16x16x32_bf16(bfr[ni], af[mi], acc[mi][ni], 0, 0, 0);
                else
                    acc[mi][ni] = __builtin_amdgcn_mfma_f32_16x16x32_bf16(af[mi], bfr[ni], acc[mi][ni], 0, 0, 0);
            }
        __builtin_amdgcn_s_setprio(0);
    }

    if (MODE == 1) {
        #pragma unroll
        for (int mi = 0; mi < 8; ++mi) {
            #pragma unroll
            for (int ni = 0; ni < 4; ++ni) {
                const int n = ntile * 256 + wn * 64 + ni * 16 + (lane & 15);
                #pragma unroll
                for (int j = 0; j < 4; ++j) {
                    const int m = mtile * 256 + wm * 128 + mi * 16 + (lane >> 4) * 4 + j;
                    Cout[(size_t)m * 1024 + n] = acc[mi][ni][j];
                }
            }
        }
    } else {
        const int seg = ntile >> 2;               // 0:V 1:G 2:T 3:R (block-uniform)
        #pragma unroll
        for (int mi = 0; mi < 8; ++mi) {
            const int m = mtile * 256 + wm * 128 + mi * 16 + (lane & 15);
            #pragma unroll
            for (int ni = 0; ni < 4; ++ni) {
                #pragma unroll
                for (int j = 0; j < 4; ++j) {
                    const int d = (ntile & 3) * 256 + wn * 64 + ni * 16 + (lane >> 4) * 4 + j;
                    const float val = acc[mi][ni][j];
                    if (seg == 0) {
                        Vt[(size_t)d * MTOT + m] = f2bf(val + bp[1 + d]);
                    } else if (seg == 1) {
                        Gt[(size_t)d * MTOT + m] = f2bf(sigm(val));
                    } else if (seg == 2) {
                        Tt[(size_t)d * MTOT + m] = f2bf(tanh_fast(val));
                    } else {
                        Rt[(size_t)d * MTOT + m] = f2bf(sigm(val));
                    }
                }
            }
        }
    }
}

// ---- K3: LDS-free sequential dual cumsum over transposed planes -------------
__global__ __launch_bounds__(64) void scan_t(
    const u16* __restrict__ Vt, const u16* __restrict__ Gt,
    const u16* __restrict__ Tt, const u16* __restrict__ Rt,
    const float* __restrict__ ub, u16* __restrict__ outb,
    float* __restrict__ act_last, float* __restrict__ gho_last)
{
    const int lane = threadIdx.x;
    const int b  = blockIdx.x >> 4;
    const int d  = ((blockIdx.x & 15) << 6) + lane;
    const int bm0 = b * T_LEN;
    const size_t rbase = (size_t)d * MTOT + bm0;
    const us8* pv = (const us8*)(Vt + rbase);
    const us8* pg = (const us8*)(Gt + rbase);
    const us8* pt = (const us8*)(Tt + rbase);
    const us8* pr = (const us8*)(Rt + rbase);

    us8 cv[2], cg[2], ct_[2], cr[2];
    #pragma unroll
    for (int h = 0; h < 2; ++h) { cv[h] = pv[h]; cg[h] = pg[h]; ct_[h] = pt[h]; cr[h] = pr[h]; }

    float acc_a = 0.f;
    _Float16 acc_g = (_Float16)0.f;

    for (int c = 0; c < 256; ++c) {
        const int cn = (c < 255) ? c + 1 : c;
        us8 nv[2], ng[2], nt2[2], nr[2];
        #pragma unroll
        for (int h = 0; h < 2; ++h) {
            nv[h] = pv[cn * 2 + h]; ng[h] = pg[cn * 2 + h];
            nt2[h] = pt[cn * 2 + h]; nr[h] = pr[cn * 2 + h];
        }
        #pragma unroll
        for (int s = 0; s < 16; ++s) {
            const int h = s >> 3, e = s & 7;
            const int t = c * 16 + s;
            const float v  = bf2f(cv[h][e]);
            const float g  = bf2f(cg[h][e]);
            const float th = bf2f(ct_[h][e]);
            const float r  = bf2f(cr[h][e]);
            const float uu = ub[bm0 + t];                 // uniform -> s_load
            acc_a = fmaf(uu, v, acc_a);                   // f32 sequential cumsum
            acc_g = acc_g + (_Float16)(g * th);           // fp16 RNE sequential cumsum
            const float comb = acc_a + (float)acc_g;
            outb[(size_t)(bm0 + t) * HD + d] = f2bf(r * comb);
        }
        #pragma unroll
        for (int h = 0; h < 2; ++h) { cv[h] = nv[h]; cg[h] = ng[h]; ct_[h] = nt2[h]; cr[h] = nr[h]; }
    }
    act_last[(size_t)b * HD + d] = acc_a;
    gho_last[(size_t)b * HD + d] = (float)acc_g;
}

extern "C" void kernel_launch(void* const* d_in, const int* in_sizes, int n_in,
                              void* d_out, int out_size, void* d_ws, size_t ws_size,
                              hipStream_t stream)
{
    const float* x   = (const float*)d_in[0];
    const float* gam = (const float*)d_in[1];
    const float* bet = (const float*)d_in[2];
    const float* Wp  = (const float*)d_in[3];
    const float* bp  = (const float*)d_in[4];
    const float* Wg  = (const float*)d_in[5];
    const float* Wt  = (const float*)d_in[6];
    const float* Wr  = (const float*)d_in[7];
    const float* Wo  = (const float*)d_in[8];

    float* out0     = (float*)d_out;                       // (B,T,H) f32
    float* act_last = out0 + (size_t)MTOT * HD;            // (B,D) f32
    float* gho_last = act_last + (size_t)B_SZ * HD;        // (B,D) fp16-valued f32

    char* ws = (char*)d_ws;
    const size_t SZ = (size_t)MTOT * HD * 2;               // 64 MiB per bf16 plane
    u16* xnb  = (u16*)(ws);                                // xn bf16; later scan output
    u16* Vt   = (u16*)(ws + SZ);                           // transposed planes [d][MTOT]
    u16* Gt   = (u16*)(ws + 2 * SZ);
    u16* Tt   = (u16*)(ws + 3 * SZ);
    u16* Rt   = (u16*)(ws + 4 * SZ);
    u16* wcat = (u16*)(ws + 5 * SZ);                       // 8,388,608 B
    u16* wob  = (u16*)(ws + 5 * SZ + 8388608);             // 2,097,152 B
    float* ub = (float*)(ws + 5 * SZ + 8388608 + 2097152); // 131,072 B

    prep_weights<<<5120, 256, 0, stream>>>(Wp, Wg, Wt, Wr, Wo, wcat, wob);
    ln_kernel<<<MTOT, 256, 0, stream>>>(x, gam, bet, Wp, bp, xnb, ub);
    gemm256<0><<<dim3(128, 16), 512, 0, stream>>>(xnb, wcat, bp, Vt, Gt, Tt, Rt, nullptr);
    scan_t<<<128, 64, 0, stream>>>(Vt, Gt, Tt, Rt, ub, xnb /*out*/, act_last, gho_last);
    gemm256<1><<<dim3(128, 4), 512, 0, stream>>>(xnb, wob, bp, nullptr, nullptr, nullptr, nullptr, out0);
}

// Round 9
// 897.597 us; speedup vs baseline: 1.1071x; 1.0196x over previous
//
#include <hip/hip_runtime.h>
#include <cstdint>
#include <cstddef>

#define B_SZ 8
#define T_LEN 4096
#define HD 1024
#define MTOT (B_SZ * T_LEN)   // 32768 tokens

typedef unsigned short u16;
typedef __attribute__((ext_vector_type(8))) short bf16x8;
typedef __attribute__((ext_vector_type(8))) unsigned short us8;
typedef __attribute__((ext_vector_type(4))) float f32x4;

static __device__ __forceinline__ float bf2f(u16 u) {
    union { unsigned i; float f; } v; v.i = ((unsigned)u) << 16; return v.f;
}
static __device__ __forceinline__ u16 f2bf(float f) {
    union { float f; unsigned i; } v; v.f = f;
    unsigned r = v.i + 0x7fffu + ((v.i >> 16) & 1u);
    return (u16)(r >> 16);
}
static __device__ __forceinline__ float sigm(float x) { return 1.f / (1.f + __expf(-x)); }
static __device__ __forceinline__ float tanh_fast(float x) { return 1.f - 2.f / (1.f + __expf(2.f * x)); }

static __device__ __forceinline__ void gload_lds16(const void* g, void* l) {
    __builtin_amdgcn_global_load_lds((const __attribute__((address_space(1))) void*)g,
                                     (__attribute__((address_space(3))) void*)l, 16, 0, 0);
}

// ---- K0: weights f32 -> bf16: wcat = [v(1024); g(1024); t(1024); r(1024)], wob = Wo
__global__ __launch_bounds__(256) void prep_weights(
    const float* __restrict__ Wp, const float* __restrict__ Wg,
    const float* __restrict__ Wt, const float* __restrict__ Wr,
    const float* __restrict__ Wo, u16* __restrict__ wcat, u16* __restrict__ wob)
{
    int i = blockIdx.x * 256 + threadIdx.x;   // float4 index
    const int T1 = 4096 * 256;
    const int T2 = 1024 * 256;
    if (i < T1) {
        int r = i >> 8, kq = i & 255;
        float4 v;
        if      (r < 1024)  v = ((const float4*)Wp)[(size_t)(r + 1) * 256 + kq];   // v-rows: Wp[1..1024]
        else if (r < 2048)  v = ((const float4*)Wg)[(size_t)(r - 1024) * 256 + kq];
        else if (r < 3072)  v = ((const float4*)Wt)[(size_t)(r - 2048) * 256 + kq];
        else                v = ((const float4*)Wr)[(size_t)(r - 3072) * 256 + kq];
        ushort4 o; o.x = f2bf(v.x); o.y = f2bf(v.y); o.z = f2bf(v.z); o.w = f2bf(v.w);
        ((ushort4*)wcat)[i] = o;
    } else if (i < T1 + T2) {
        int j = i - T1;
        float4 v = ((const float4*)Wo)[j];
        ushort4 o; o.x = f2bf(v.x); o.y = f2bf(v.y); o.z = f2bf(v.z); o.w = f2bf(v.w);
        ((ushort4*)wob)[j] = o;
    }
}

// ---- K1: LayerNorm (f32) -> xn bf16, fused u[m] = xn_f32 . Wp[0] + bp[0] ----
__global__ __launch_bounds__(256) void ln_kernel(
    const float* __restrict__ x, const float* __restrict__ gamma,
    const float* __restrict__ beta, const float* __restrict__ Wp,
    const float* __restrict__ bp, u16* __restrict__ xnb, float* __restrict__ u)
{
    __shared__ float red[8];
    const int row = blockIdx.x, tid = threadIdx.x;
    const float4 v = ((const float4*)(x + (size_t)row * HD))[tid];
    float s  = v.x + v.y + v.z + v.w;
    float sq = v.x * v.x + v.y * v.y + v.z * v.z + v.w * v.w;
    #pragma unroll
    for (int off = 32; off > 0; off >>= 1) {
        s  += __shfl_down(s, off);
        sq += __shfl_down(sq, off);
    }
    if ((tid & 63) == 0) { red[tid >> 6] = s; red[4 + (tid >> 6)] = sq; }
    __syncthreads();
    const float S   = red[0] + red[1] + red[2] + red[3];
    const float SQ  = red[4] + red[5] + red[6] + red[7];
    const float mu  = S * (1.f / HD);
    const float var = SQ * (1.f / HD) - mu * mu;
    const float rs  = rsqrtf(var + 1e-5f);
    const float4 gg = ((const float4*)gamma)[tid];
    const float4 bb = ((const float4*)beta)[tid];
    const float x0 = (v.x - mu) * rs * gg.x + bb.x;
    const float x1 = (v.y - mu) * rs * gg.y + bb.y;
    const float x2 = (v.z - mu) * rs * gg.z + bb.z;
    const float x3 = (v.w - mu) * rs * gg.w + bb.w;
    ushort4 o; o.x = f2bf(x0); o.y = f2bf(x1); o.z = f2bf(x2); o.w = f2bf(x3);
    ((ushort4*)(xnb + (size_t)row * HD))[tid] = o;
    const float4 w0 = ((const float4*)Wp)[tid];
    float su = x0 * w0.x + x1 * w0.y + x2 * w0.z + x3 * w0.w;
    #pragma unroll
    for (int off = 32; off > 0; off >>= 1) su += __shfl_down(su, off);
    __syncthreads();
    if ((tid & 63) == 0) red[tid >> 6] = su;
    __syncthreads();
    if (tid == 0) u[row] = red[0] + red[1] + red[2] + red[3] + bp[0];
}

// ---- K2/K4: bf16 MFMA GEMM, 256x256 tile, 8 waves (2M x 4N), BK=32.
// Depth-1 pipeline, one barrier pair per K-slab (round-8 structure, verified).
// LDS swizzle FIX (round 9): stored chunk cs of row r holds global chunk
//   cg = cs ^ ((r>>1)&3)   => bank-quad = (4r + cs) mod 8 sweeps ALL 8 quads
// over any 8 consecutive rows (round 8's cg^(r&3) only reached 4 of 8 ->
// measured 2.5e7 conflict cycles). Read side: cl = (lane>>4) ^ ((lane>>1)&3).
// MODE 0: swapped-operand MFMA -> transposed; writes bf16 planes [d][MTOT].
// MODE 1: normal orientation, f32 [m][1024] store.
template<int MODE>
__global__ __launch_bounds__(512) void gemm256(
    const u16* __restrict__ A, const u16* __restrict__ W,
    const float* __restrict__ bp,
    u16* __restrict__ Vt, u16* __restrict__ Gt, u16* __restrict__ Tt, u16* __restrict__ Rt,
    float* __restrict__ Cout)
{
    __shared__ u16 sA[2][256 * 32];   // 32 KiB
    __shared__ u16 sB[2][256 * 32];   // 32 KiB
    const int mtile = blockIdx.x, ntile = blockIdx.y;
    const int tid = threadIdx.x;
    const int lane = tid & 63, wave = tid >> 6;
    const int wm = wave >> 2, wn = wave & 3;     // 2M x 4N wave grid
    const u16* Ab = A + (size_t)mtile * 256 * 1024;
    const u16* Wb = W + (size_t)ntile * 256 * 1024;

    // staging: slab = 1024 chunks (16B); thread stages chunks tid and tid+512 of A and B.
    // stored chunk cs holds global chunk cg = cs ^ ((r>>1)&3) (inverse-swz source, linear dest)
    int goff[2], loff[2];
    #pragma unroll
    for (int jj = 0; jj < 2; ++jj) {
        const int q = jj * 512 + tid;
        const int r = q >> 2;
        goff[jj] = r * 1024 + ((q & 3) ^ ((r >> 1) & 3)) * 8;
        loff[jj] = q * 8;
    }
    auto stage = [&](int pb, int kt) {
        #pragma unroll
        for (int jj = 0; jj < 2; ++jj) {
            gload_lds16(Ab + goff[jj] + kt * 32, &sA[pb][loff[jj]]);
            gload_lds16(Wb + goff[jj] + kt * 32, &sB[pb][loff[jj]]);
        }
    };

    f32x4 acc[8][4] = {};
    const int cl = (lane >> 4) ^ ((lane >> 1) & 3);   // swizzled chunk (frag rows 16-aligned)
    const int aoff = (wm * 128 + (lane & 15)) * 32 + cl * 8;
    const int boff = (wn * 64 + (lane & 15)) * 32 + cl * 8;

    stage(0, 0);
    for (int t = 0; t < 32; ++t) {
        const int p = t & 1;
        asm volatile("s_waitcnt vmcnt(0)" ::: "memory");   // slab t (issued last phase) landed
        __builtin_amdgcn_sched_barrier(0);
        __builtin_amdgcn_s_barrier();                      // all waves' slab-t writes visible
        __builtin_amdgcn_sched_barrier(0);
        if (t < 31) stage(p ^ 1, t + 1);                   // overwrites slab t-1's buffer: readers done pre-barrier
        bf16x8 af[8], bfr[4];
        #pragma unroll
        for (int mi = 0; mi < 8; ++mi)
            af[mi] = *(const bf16x8*)(&sA[p][aoff + mi * 512]);
        #pragma unroll
        for (int ni = 0; ni < 4; ++ni)
            bfr[ni] = *(const bf16x8*)(&sB[p][boff + ni * 512]);
        __builtin_amdgcn_s_setprio(1);
        #pragma unroll
        for (int mi = 0; mi < 8; ++mi)
            #pragma unroll
            for (int ni = 0; ni < 4; ++ni) {
                if (MODE == 0)   // swapped operands -> D[d][m] (transposed)
                    acc[mi][ni] = __builtin_amdgcn_mfma_f32_16x16x32_bf16(bfr[ni], af[mi], acc[mi][ni], 0, 0, 0);
                else
                    acc[mi][ni] = __builtin_amdgcn_mfma_f32_16x16x32_bf16(af[mi], bfr[ni], acc[mi][ni], 0, 0, 0);
            }
        __builtin_amdgcn_s_setprio(0);
    }

    if (MODE == 1) {
        #pragma unroll
        for (int mi = 0; mi < 8; ++mi) {
            #pragma unroll
            for (int ni = 0; ni < 4; ++ni) {
                const int n = ntile * 256 + wn * 64 + ni * 16 + (lane & 15);
                #pragma unroll
                for (int j = 0; j < 4; ++j) {
                    const int m = mtile * 256 + wm * 128 + mi * 16 + (lane >> 4) * 4 + j;
                    Cout[(size_t)m * 1024 + n] = acc[mi][ni][j];
                }
            }
        }
    } else {
        const int seg = ntile >> 2;               // 0:V 1:G 2:T 3:R (block-uniform)
        #pragma unroll
        for (int mi = 0; mi < 8; ++mi) {
            const int m = mtile * 256 + wm * 128 + mi * 16 + (lane & 15);
            #pragma unroll
            for (int ni = 0; ni < 4; ++ni) {
                #pragma unroll
                for (int j = 0; j < 4; ++j) {
                    const int d = (ntile & 3) * 256 + wn * 64 + ni * 16 + (lane >> 4) * 4 + j;
                    const float val = acc[mi][ni][j];
                    if (seg == 0) {
                        Vt[(size_t)d * MTOT + m] = f2bf(val + bp[1 + d]);
                    } else if (seg == 1) {
                        Gt[(size_t)d * MTOT + m] = f2bf(sigm(val));
                    } else if (seg == 2) {
                        Tt[(size_t)d * MTOT + m] = f2bf(tanh_fast(val));
                    } else {
                        Rt[(size_t)d * MTOT + m] = f2bf(sigm(val));
                    }
                }
            }
        }
    }
}

// ---- K3: LDS-free sequential dual cumsum over transposed planes -------------
__global__ __launch_bounds__(64) void scan_t(
    const u16* __restrict__ Vt, const u16* __restrict__ Gt,
    const u16* __restrict__ Tt, const u16* __restrict__ Rt,
    const float* __restrict__ ub, u16* __restrict__ outb,
    float* __restrict__ act_last, float* __restrict__ gho_last)
{
    const int lane = threadIdx.x;
    const int b  = blockIdx.x >> 4;
    const int d  = ((blockIdx.x & 15) << 6) + lane;
    const int bm0 = b * T_LEN;
    const size_t rbase = (size_t)d * MTOT + bm0;
    const us8* pv = (const us8*)(Vt + rbase);
    const us8* pg = (const us8*)(Gt + rbase);
    const us8* pt = (const us8*)(Tt + rbase);
    const us8* pr = (const us8*)(Rt + rbase);

    us8 cv[2], cg[2], ct_[2], cr[2];
    #pragma unroll
    for (int h = 0; h < 2; ++h) { cv[h] = pv[h]; cg[h] = pg[h]; ct_[h] = pt[h]; cr[h] = pr[h]; }

    float acc_a = 0.f;
    _Float16 acc_g = (_Float16)0.f;

    for (int c = 0; c < 256; ++c) {
        const int cn = (c < 255) ? c + 1 : c;
        us8 nv[2], ng[2], nt2[2], nr[2];
        #pragma unroll
        for (int h = 0; h < 2; ++h) {
            nv[h] = pv[cn * 2 + h]; ng[h] = pg[cn * 2 + h];
            nt2[h] = pt[cn * 2 + h]; nr[h] = pr[cn * 2 + h];
        }
        #pragma unroll
        for (int s = 0; s < 16; ++s) {
            const int h = s >> 3, e = s & 7;
            const int t = c * 16 + s;
            const float v  = bf2f(cv[h][e]);
            const float g  = bf2f(cg[h][e]);
            const float th = bf2f(ct_[h][e]);
            const float r  = bf2f(cr[h][e]);
            const float uu = ub[bm0 + t];                 // uniform -> s_load
            acc_a = fmaf(uu, v, acc_a);                   // f32 sequential cumsum
            acc_g = acc_g + (_Float16)(g * th);           // fp16 RNE sequential cumsum
            const float comb = acc_a + (float)acc_g;
            outb[(size_t)(bm0 + t) * HD + d] = f2bf(r * comb);
        }
        #pragma unroll
        for (int h = 0; h < 2; ++h) { cv[h] = nv[h]; cg[h] = ng[h]; ct_[h] = nt2[h]; cr[h] = nr[h]; }
    }
    act_last[(size_t)b * HD + d] = acc_a;
    gho_last[(size_t)b * HD + d] = (float)acc_g;
}

extern "C" void kernel_launch(void* const* d_in, const int* in_sizes, int n_in,
                              void* d_out, int out_size, void* d_ws, size_t ws_size,
                              hipStream_t stream)
{
    const float* x   = (const float*)d_in[0];
    const float* gam = (const float*)d_in[1];
    const float* bet = (const float*)d_in[2];
    const float* Wp  = (const float*)d_in[3];
    const float* bp  = (const float*)d_in[4];
    const float* Wg  = (const float*)d_in[5];
    const float* Wt  = (const float*)d_in[6];
    const float* Wr  = (const float*)d_in[7];
    const float* Wo  = (const float*)d_in[8];

    float* out0     = (float*)d_out;                       // (B,T,H) f32
    float* act_last = out0 + (size_t)MTOT * HD;            // (B,D) f32
    float* gho_last = act_last + (size_t)B_SZ * HD;        // (B,D) fp16-valued f32

    char* ws = (char*)d_ws;
    const size_t SZ = (size_t)MTOT * HD * 2;               // 64 MiB per bf16 plane
    u16* xnb  = (u16*)(ws);                                // xn bf16; later scan output
    u16* Vt   = (u16*)(ws + SZ);                           // transposed planes [d][MTOT]
    u16* Gt   = (u16*)(ws + 2 * SZ);
    u16* Tt   = (u16*)(ws + 3 * SZ);
    u16* Rt   = (u16*)(ws + 4 * SZ);
    u16* wcat = (u16*)(ws + 5 * SZ);                       // 8,388,608 B
    u16* wob  = (u16*)(ws + 5 * SZ + 8388608);             // 2,097,152 B
    float* ub = (float*)(ws + 5 * SZ + 8388608 + 2097152); // 131,072 B

    prep_weights<<<5120, 256, 0, stream>>>(Wp, Wg, Wt, Wr, Wo, wcat, wob);
    ln_kernel<<<MTOT, 256, 0, stream>>>(x, gam, bet, Wp, bp, xnb, ub);
    gemm256<0><<<dim3(128, 16), 512, 0, stream>>>(xnb, wcat, bp, Vt, Gt, Tt, Rt, nullptr);
    scan_t<<<128, 64, 0, stream>>>(Vt, Gt, Tt, Rt, ub, xnb /*out*/, act_last, gho_last);
    gemm256<1><<<dim3(128, 4), 512, 0, stream>>>(xnb, wob, bp, nullptr, nullptr, nullptr, nullptr, out0);
}

// Round 10
// 866.075 us; speedup vs baseline: 1.1474x; 1.0364x over previous
//
#include <hip/hip_runtime.h>
#include <cstdint>
#include <cstddef>

#define B_SZ 8
#define T_LEN 4096
#define HD 1024
#define MTOT (B_SZ * T_LEN)   // 32768 tokens

typedef unsigned short u16;
typedef __attribute__((ext_vector_type(8))) short bf16x8;
typedef __attribute__((ext_vector_type(8))) unsigned short us8;
typedef __attribute__((ext_vector_type(4))) float f32x4;

static __device__ __forceinline__ float bf2f(u16 u) {
    union { unsigned i; float f; } v; v.i = ((unsigned)u) << 16; return v.f;
}
static __device__ __forceinline__ u16 f2bf(float f) {
    union { float f; unsigned i; } v; v.f = f;
    unsigned r = v.i + 0x7fffu + ((v.i >> 16) & 1u);
    return (u16)(r >> 16);
}
static __device__ __forceinline__ float sigm(float x) { return 1.f / (1.f + __expf(-x)); }
static __device__ __forceinline__ float tanh_fast(float x) { return 1.f - 2.f / (1.f + __expf(2.f * x)); }

static __device__ __forceinline__ void gload_lds16(const void* g, void* l) {
    __builtin_amdgcn_global_load_lds((const __attribute__((address_space(1))) void*)g,
                                     (__attribute__((address_space(3))) void*)l, 16, 0, 0);
}

// ---- K0: weights f32 -> bf16: wcat = [v(1024); g(1024); t(1024); r(1024)], wob = Wo
__global__ __launch_bounds__(256) void prep_weights(
    const float* __restrict__ Wp, const float* __restrict__ Wg,
    const float* __restrict__ Wt, const float* __restrict__ Wr,
    const float* __restrict__ Wo, u16* __restrict__ wcat, u16* __restrict__ wob)
{
    int i = blockIdx.x * 256 + threadIdx.x;   // float4 index
    const int T1 = 4096 * 256;
    const int T2 = 1024 * 256;
    if (i < T1) {
        int r = i >> 8, kq = i & 255;
        float4 v;
        if      (r < 1024)  v = ((const float4*)Wp)[(size_t)(r + 1) * 256 + kq];   // v-rows: Wp[1..1024]
        else if (r < 2048)  v = ((const float4*)Wg)[(size_t)(r - 1024) * 256 + kq];
        else if (r < 3072)  v = ((const float4*)Wt)[(size_t)(r - 2048) * 256 + kq];
        else                v = ((const float4*)Wr)[(size_t)(r - 3072) * 256 + kq];
        ushort4 o; o.x = f2bf(v.x); o.y = f2bf(v.y); o.z = f2bf(v.z); o.w = f2bf(v.w);
        ((ushort4*)wcat)[i] = o;
    } else if (i < T1 + T2) {
        int j = i - T1;
        float4 v = ((const float4*)Wo)[j];
        ushort4 o; o.x = f2bf(v.x); o.y = f2bf(v.y); o.z = f2bf(v.z); o.w = f2bf(v.w);
        ((ushort4*)wob)[j] = o;
    }
}

// ---- K1: LayerNorm (f32) -> xn bf16, fused u[m] = xn_f32 . Wp[0] + bp[0] ----
__global__ __launch_bounds__(256) void ln_kernel(
    const float* __restrict__ x, const float* __restrict__ gamma,
    const float* __restrict__ beta, const float* __restrict__ Wp,
    const float* __restrict__ bp, u16* __restrict__ xnb, float* __restrict__ u)
{
    __shared__ float red[8];
    const int row = blockIdx.x, tid = threadIdx.x;
    const float4 v = ((const float4*)(x + (size_t)row * HD))[tid];
    float s  = v.x + v.y + v.z + v.w;
    float sq = v.x * v.x + v.y * v.y + v.z * v.z + v.w * v.w;
    #pragma unroll
    for (int off = 32; off > 0; off >>= 1) {
        s  += __shfl_down(s, off);
        sq += __shfl_down(sq, off);
    }
    if ((tid & 63) == 0) { red[tid >> 6] = s; red[4 + (tid >> 6)] = sq; }
    __syncthreads();
    const float S   = red[0] + red[1] + red[2] + red[3];
    const float SQ  = red[4] + red[5] + red[6] + red[7];
    const float mu  = S * (1.f / HD);
    const float var = SQ * (1.f / HD) - mu * mu;
    const float rs  = rsqrtf(var + 1e-5f);
    const float4 gg = ((const float4*)gamma)[tid];
    const float4 bb = ((const float4*)beta)[tid];
    const float x0 = (v.x - mu) * rs * gg.x + bb.x;
    const float x1 = (v.y - mu) * rs * gg.y + bb.y;
    const float x2 = (v.z - mu) * rs * gg.z + bb.z;
    const float x3 = (v.w - mu) * rs * gg.w + bb.w;
    ushort4 o; o.x = f2bf(x0); o.y = f2bf(x1); o.z = f2bf(x2); o.w = f2bf(x3);
    ((ushort4*)(xnb + (size_t)row * HD))[tid] = o;
    const float4 w0 = ((const float4*)Wp)[tid];
    float su = x0 * w0.x + x1 * w0.y + x2 * w0.z + x3 * w0.w;
    #pragma unroll
    for (int off = 32; off > 0; off >>= 1) su += __shfl_down(su, off);
    __syncthreads();
    if ((tid & 63) == 0) red[tid >> 6] = su;
    __syncthreads();
    if (tid == 0) u[row] = red[0] + red[1] + red[2] + red[3] + bp[0];
}

// ---- K2/K4: bf16 MFMA GEMM, 256x256 tile, 8 waves (2M x 4N), BK=32.
// Depth-2 counted-vmcnt pipeline, TRIPLE-buffered LDS (96 KiB):
//   prologue: stage slab0->buf0, slab1->buf1
//   slab t:   s_waitcnt vmcnt(4)  [slab t's 4 loads done; slab t+1's in flight]
//             fenced s_barrier; stage slab t+2 -> buf (t+2)%3;
//             12 ds_read + 32 MFMA from buf t%3
// Buffer written at t was last READ at t-1 (one barrier margin, sched-fenced).
// vmcnt never drains to 0 in steady state (T4); tail only.
// LDS swizzle (verified r9, conflicts=0): stored chunk cs of row r holds global
// chunk cg = cs ^ ((r>>1)&3); read cl = (lane>>4) ^ ((lane>>1)&3).
// MODE 0: swapped-operand MFMA -> transposed; bf16 planes [d][MTOT];
//         store loops mi-INNERMOST so each 64B line completes in 2 instrs.
// MODE 1: normal orientation, f32 [m][1024] store (lines complete per instr).
template<int MODE>
__global__ __launch_bounds__(512) void gemm256(
    const u16* __restrict__ A, const u16* __restrict__ W,
    const float* __restrict__ bp,
    u16* __restrict__ Vt, u16* __restrict__ Gt, u16* __restrict__ Tt, u16* __restrict__ Rt,
    float* __restrict__ Cout)
{
    __shared__ u16 sA[3][256 * 32];   // 48 KiB
    __shared__ u16 sB[3][256 * 32];   // 48 KiB
    const int mtile = blockIdx.x, ntile = blockIdx.y;
    const int tid = threadIdx.x;
    const int lane = tid & 63, wave = tid >> 6;
    const int wm = wave >> 2, wn = wave & 3;     // 2M x 4N wave grid
    const u16* Ab = A + (size_t)mtile * 256 * 1024;
    const u16* Wb = W + (size_t)ntile * 256 * 1024;

    // staging: slab = 1024 chunks (16B); thread stages chunks tid and tid+512 of A and B.
    int goff[2], loff[2];
    #pragma unroll
    for (int jj = 0; jj < 2; ++jj) {
        const int q = jj * 512 + tid;
        const int r = q >> 2;
        goff[jj] = r * 1024 + ((q & 3) ^ ((r >> 1) & 3)) * 8;
        loff[jj] = q * 8;
    }
    auto stage = [&](int pb, int kt) {
        #pragma unroll
        for (int jj = 0; jj < 2; ++jj) {
            gload_lds16(Ab + goff[jj] + kt * 32, &sA[pb][loff[jj]]);
            gload_lds16(Wb + goff[jj] + kt * 32, &sB[pb][loff[jj]]);
        }
    };

    f32x4 acc[8][4] = {};
    const int cl = (lane >> 4) ^ ((lane >> 1) & 3);   // swizzled chunk (frag rows 16-aligned)
    const int aoff = (wm * 128 + (lane & 15)) * 32 + cl * 8;
    const int boff = (wn * 64 + (lane & 15)) * 32 + cl * 8;

    stage(0, 0);
    stage(1, 1);
    int rb = 0;                                        // read buffer = t % 3
    for (int t = 0; t < 32; ++t) {
        if (t < 31) asm volatile("s_waitcnt vmcnt(4)" ::: "memory");  // slab t landed
        else        asm volatile("s_waitcnt vmcnt(0)" ::: "memory");  // tail drain
        __builtin_amdgcn_sched_barrier(0);
        __builtin_amdgcn_s_barrier();                  // all waves' slab-t writes visible
        __builtin_amdgcn_sched_barrier(0);
        if (t < 30) {
            const int wb = (rb >= 1) ? rb - 1 : 2;     // (t+2) % 3
            stage(wb, t + 2);                          // last read at t-1, pre-barrier
            __builtin_amdgcn_sched_barrier(0);
        }
        bf16x8 af[8], bfr[4];
        #pragma unroll
        for (int mi = 0; mi < 8; ++mi)
            af[mi] = *(const bf16x8*)(&sA[rb][aoff + mi * 512]);
        #pragma unroll
        for (int ni = 0; ni < 4; ++ni)
            bfr[ni] = *(const bf16x8*)(&sB[rb][boff + ni * 512]);
        __builtin_amdgcn_s_setprio(1);
        #pragma unroll
        for (int mi = 0; mi < 8; ++mi)
            #pragma unroll
            for (int ni = 0; ni < 4; ++ni) {
                if (MODE == 0)   // swapped operands -> D[d][m] (transposed)
                    acc[mi][ni] = __builtin_amdgcn_mfma_f32_16x16x32_bf16(bfr[ni], af[mi], acc[mi][ni], 0, 0, 0);
                else
                    acc[mi][ni] = __builtin_amdgcn_mfma_f32_16x16x32_bf16(af[mi], bfr[ni], acc[mi][ni], 0, 0, 0);
            }
        __builtin_amdgcn_s_setprio(0);
        rb = (rb == 2) ? 0 : rb + 1;
    }

    if (MODE == 1) {
        #pragma unroll
        for (int mi = 0; mi < 8; ++mi) {
            #pragma unroll
            for (int ni = 0; ni < 4; ++ni) {
                const int n = ntile * 256 + wn * 64 + ni * 16 + (lane & 15);
                #pragma unroll
                for (int j = 0; j < 4; ++j) {
                    const int m = mtile * 256 + wm * 128 + mi * 16 + (lane >> 4) * 4 + j;
                    Cout[(size_t)m * 1024 + n] = acc[mi][ni][j];
                }
            }
        }
    } else {
        const int seg = ntile >> 2;               // 0:V 1:G 2:T 3:R (block-uniform)
        #pragma unroll
        for (int ni = 0; ni < 4; ++ni) {
            #pragma unroll
            for (int j = 0; j < 4; ++j) {
                const int d = (ntile & 3) * 256 + wn * 64 + ni * 16 + (lane >> 4) * 4 + j;
                const size_t drow = (size_t)d * MTOT;
                const int mbase = mtile * 256 + wm * 128 + (lane & 15);
                #pragma unroll
                for (int mi = 0; mi < 8; ++mi) {          // mi innermost: line done in 2 instrs
                    const int m = mbase + mi * 16;
                    const float val = acc[mi][ni][j];
                    if (seg == 0) {
                        Vt[drow + m] = f2bf(val + bp[1 + d]);
                    } else if (seg == 1) {
                        Gt[drow + m] = f2bf(sigm(val));
                    } else if (seg == 2) {
                        Tt[drow + m] = f2bf(tanh_fast(val));
                    } else {
                        Rt[drow + m] = f2bf(sigm(val));
                    }
                }
            }
        }
    }
}

// ---- K3: LDS-free sequential dual cumsum over transposed planes -------------
__global__ __launch_bounds__(64) void scan_t(
    const u16* __restrict__ Vt, const u16* __restrict__ Gt,
    const u16* __restrict__ Tt, const u16* __restrict__ Rt,
    const float* __restrict__ ub, u16* __restrict__ outb,
    float* __restrict__ act_last, float* __restrict__ gho_last)
{
    const int lane = threadIdx.x;
    const int b  = blockIdx.x >> 4;
    const int d  = ((blockIdx.x & 15) << 6) + lane;
    const int bm0 = b * T_LEN;
    const size_t rbase = (size_t)d * MTOT + bm0;
    const us8* pv = (const us8*)(Vt + rbase);
    const us8* pg = (const us8*)(Gt + rbase);
    const us8* pt = (const us8*)(Tt + rbase);
    const us8* pr = (const us8*)(Rt + rbase);

    us8 cv[2], cg[2], ct_[2], cr[2];
    #pragma unroll
    for (int h = 0; h < 2; ++h) { cv[h] = pv[h]; cg[h] = pg[h]; ct_[h] = pt[h]; cr[h] = pr[h]; }

    float acc_a = 0.f;
    _Float16 acc_g = (_Float16)0.f;

    for (int c = 0; c < 256; ++c) {
        const int cn = (c < 255) ? c + 1 : c;
        us8 nv[2], ng[2], nt2[2], nr[2];
        #pragma unroll
        for (int h = 0; h < 2; ++h) {
            nv[h] = pv[cn * 2 + h]; ng[h] = pg[cn * 2 + h];
            nt2[h] = pt[cn * 2 + h]; nr[h] = pr[cn * 2 + h];
        }
        #pragma unroll
        for (int s = 0; s < 16; ++s) {
            const int h = s >> 3, e = s & 7;
            const int t = c * 16 + s;
            const float v  = bf2f(cv[h][e]);
            const float g  = bf2f(cg[h][e]);
            const float th = bf2f(ct_[h][e]);
            const float r  = bf2f(cr[h][e]);
            const float uu = ub[bm0 + t];                 // uniform -> s_load
            acc_a = fmaf(uu, v, acc_a);                   // f32 sequential cumsum
            acc_g = acc_g + (_Float16)(g * th);           // fp16 RNE sequential cumsum
            const float comb = acc_a + (float)acc_g;
            outb[(size_t)(bm0 + t) * HD + d] = f2bf(r * comb);
        }
        #pragma unroll
        for (int h = 0; h < 2; ++h) { cv[h] = nv[h]; cg[h] = ng[h]; ct_[h] = nt2[h]; cr[h] = nr[h]; }
    }
    act_last[(size_t)b * HD + d] = acc_a;
    gho_last[(size_t)b * HD + d] = (float)acc_g;
}

extern "C" void kernel_launch(void* const* d_in, const int* in_sizes, int n_in,
                              void* d_out, int out_size, void* d_ws, size_t ws_size,
                              hipStream_t stream)
{
    const float* x   = (const float*)d_in[0];
    const float* gam = (const float*)d_in[1];
    const float* bet = (const float*)d_in[2];
    const float* Wp  = (const float*)d_in[3];
    const float* bp  = (const float*)d_in[4];
    const float* Wg  = (const float*)d_in[5];
    const float* Wt  = (const float*)d_in[6];
    const float* Wr  = (const float*)d_in[7];
    const float* Wo  = (const float*)d_in[8];

    float* out0     = (float*)d_out;                       // (B,T,H) f32
    float* act_last = out0 + (size_t)MTOT * HD;            // (B,D) f32
    float* gho_last = act_last + (size_t)B_SZ * HD;        // (B,D) fp16-valued f32

    char* ws = (char*)d_ws;
    const size_t SZ = (size_t)MTOT * HD * 2;               // 64 MiB per bf16 plane
    u16* xnb  = (u16*)(ws);                                // xn bf16; later scan output
    u16* Vt   = (u16*)(ws + SZ);                           // transposed planes [d][MTOT]
    u16* Gt   = (u16*)(ws + 2 * SZ);
    u16* Tt   = (u16*)(ws + 3 * SZ);
    u16* Rt   = (u16*)(ws + 4 * SZ);
    u16* wcat = (u16*)(ws + 5 * SZ);                       // 8,388,608 B
    u16* wob  = (u16*)(ws + 5 * SZ + 8388608);             // 2,097,152 B
    float* ub = (float*)(ws + 5 * SZ + 8388608 + 2097152); // 131,072 B

    prep_weights<<<5120, 256, 0, stream>>>(Wp, Wg, Wt, Wr, Wo, wcat, wob);
    ln_kernel<<<MTOT, 256, 0, stream>>>(x, gam, bet, Wp, bp, xnb, ub);
    gemm256<0><<<dim3(128, 16), 512, 0, stream>>>(xnb, wcat, bp, Vt, Gt, Tt, Rt, nullptr);
    scan_t<<<128, 64, 0, stream>>>(Vt, Gt, Tt, Rt, ub, xnb /*out*/, act_last, gho_last);
    gemm256<1><<<dim3(128, 4), 512, 0, stream>>>(xnb, wob, bp, nullptr, nullptr, nullptr, nullptr, out0);
}

// Round 11
// 817.508 us; speedup vs baseline: 1.2155x; 1.0594x over previous
//
#include <hip/hip_runtime.h>
#include <cstdint>
#include <cstddef>

#define B_SZ 8
#define T_LEN 4096
#define HD 1024
#define MTOT (B_SZ * T_LEN)   // 32768 tokens

typedef unsigned short u16;
typedef __attribute__((ext_vector_type(8))) short bf16x8;
typedef __attribute__((ext_vector_type(8))) unsigned short us8;
typedef __attribute__((ext_vector_type(4))) float f32x4;

static __device__ __forceinline__ float bf2f(u16 u) {
    union { unsigned i; float f; } v; v.i = ((unsigned)u) << 16; return v.f;
}
static __device__ __forceinline__ u16 f2bf(float f) {
    union { float f; unsigned i; } v; v.f = f;
    unsigned r = v.i + 0x7fffu + ((v.i >> 16) & 1u);
    return (u16)(r >> 16);
}
static __device__ __forceinline__ float sigm(float x) { return 1.f / (1.f + __expf(-x)); }
static __device__ __forceinline__ float tanh_fast(float x) { return 1.f - 2.f / (1.f + __expf(2.f * x)); }

static __device__ __forceinline__ void gload_lds16(const void* g, void* l) {
    __builtin_amdgcn_global_load_lds((const __attribute__((address_space(1))) void*)g,
                                     (__attribute__((address_space(3))) void*)l, 16, 0, 0);
}

// ---- K0: weights f32 -> bf16: wcat = [v(1024); g(1024); t(1024); r(1024)], wob = Wo
__global__ __launch_bounds__(256) void prep_weights(
    const float* __restrict__ Wp, const float* __restrict__ Wg,
    const float* __restrict__ Wt, const float* __restrict__ Wr,
    const float* __restrict__ Wo, u16* __restrict__ wcat, u16* __restrict__ wob)
{
    int i = blockIdx.x * 256 + threadIdx.x;   // float4 index
    const int T1 = 4096 * 256;
    const int T2 = 1024 * 256;
    if (i < T1) {
        int r = i >> 8, kq = i & 255;
        float4 v;
        if      (r < 1024)  v = ((const float4*)Wp)[(size_t)(r + 1) * 256 + kq];   // v-rows: Wp[1..1024]
        else if (r < 2048)  v = ((const float4*)Wg)[(size_t)(r - 1024) * 256 + kq];
        else if (r < 3072)  v = ((const float4*)Wt)[(size_t)(r - 2048) * 256 + kq];
        else                v = ((const float4*)Wr)[(size_t)(r - 3072) * 256 + kq];
        ushort4 o; o.x = f2bf(v.x); o.y = f2bf(v.y); o.z = f2bf(v.z); o.w = f2bf(v.w);
        ((ushort4*)wcat)[i] = o;
    } else if (i < T1 + T2) {
        int j = i - T1;
        float4 v = ((const float4*)Wo)[j];
        ushort4 o; o.x = f2bf(v.x); o.y = f2bf(v.y); o.z = f2bf(v.z); o.w = f2bf(v.w);
        ((ushort4*)wob)[j] = o;
    }
}

// ---- K1: LayerNorm (f32) -> xn bf16, fused u[m] = xn_f32 . Wp[0] + bp[0] ----
__global__ __launch_bounds__(256) void ln_kernel(
    const float* __restrict__ x, const float* __restrict__ gamma,
    const float* __restrict__ beta, const float* __restrict__ Wp,
    const float* __restrict__ bp, u16* __restrict__ xnb, float* __restrict__ u)
{
    __shared__ float red[8];
    const int row = blockIdx.x, tid = threadIdx.x;
    const float4 v = ((const float4*)(x + (size_t)row * HD))[tid];
    float s  = v.x + v.y + v.z + v.w;
    float sq = v.x * v.x + v.y * v.y + v.z * v.z + v.w * v.w;
    #pragma unroll
    for (int off = 32; off > 0; off >>= 1) {
        s  += __shfl_down(s, off);
        sq += __shfl_down(sq, off);
    }
    if ((tid & 63) == 0) { red[tid >> 6] = s; red[4 + (tid >> 6)] = sq; }
    __syncthreads();
    const float S   = red[0] + red[1] + red[2] + red[3];
    const float SQ  = red[4] + red[5] + red[6] + red[7];
    const float mu  = S * (1.f / HD);
    const float var = SQ * (1.f / HD) - mu * mu;
    const float rs  = rsqrtf(var + 1e-5f);
    const float4 gg = ((const float4*)gamma)[tid];
    const float4 bb = ((const float4*)beta)[tid];
    const float x0 = (v.x - mu) * rs * gg.x + bb.x;
    const float x1 = (v.y - mu) * rs * gg.y + bb.y;
    const float x2 = (v.z - mu) * rs * gg.z + bb.z;
    const float x3 = (v.w - mu) * rs * gg.w + bb.w;
    ushort4 o; o.x = f2bf(x0); o.y = f2bf(x1); o.z = f2bf(x2); o.w = f2bf(x3);
    ((ushort4*)(xnb + (size_t)row * HD))[tid] = o;
    const float4 w0 = ((const float4*)Wp)[tid];
    float su = x0 * w0.x + x1 * w0.y + x2 * w0.z + x3 * w0.w;
    #pragma unroll
    for (int off = 32; off > 0; off >>= 1) su += __shfl_down(su, off);
    __syncthreads();
    if ((tid & 63) == 0) red[tid >> 6] = su;
    __syncthreads();
    if (tid == 0) u[row] = red[0] + red[1] + red[2] + red[3] + bp[0];
}

// ---- K2/K4: bf16 MFMA GEMM, 256x256 tile, 8 waves (2M x 4N), BK=64.
// 16 K-slabs (half the sync points of r10's BK=32), double-buffered 128 KiB LDS,
// round-8-verified skeleton per slab:
//   { vmcnt(0); SB; s_barrier; SB; stage slab t+1 -> buf p^1; 2x(12 ds_read + 32 MFMA) }
// Stage loads drain a full 2-half compute phase later. Buffer overwritten at t
// was last read at t-1, pre-barrier, sched-fenced.
// LDS row = 64 u16 = 8 chunks (16B) -> bank-quad = chunk index. Swizzle:
//   store: chunk cs of row r holds global chunk cg = cs ^ (r&7)
//   read:  cs = (h*4 + (lane>>4)) ^ (lane&7)   [frag rows 16-aligned]
//   => 8 lanes per bank-quad, uniform (same construction as r9, measured 0 conflicts)
// MODE 0: swapped-operand MFMA -> transposed; bf16 planes [d][MTOT], mi-innermost stores.
// MODE 1: normal orientation, f32 [m][1024] store.
template<int MODE>
__global__ __launch_bounds__(512) void gemm256(
    const u16* __restrict__ A, const u16* __restrict__ W,
    const float* __restrict__ bp,
    u16* __restrict__ Vt, u16* __restrict__ Gt, u16* __restrict__ Tt, u16* __restrict__ Rt,
    float* __restrict__ Cout)
{
    __shared__ u16 sA[2][256 * 64];   // 64 KiB
    __shared__ u16 sB[2][256 * 64];   // 64 KiB
    const int mtile = blockIdx.x, ntile = blockIdx.y;
    const int tid = threadIdx.x;
    const int lane = tid & 63, wave = tid >> 6;
    const int wm = wave >> 2, wn = wave & 3;     // 2M x 4N wave grid
    const u16* Ab = A + (size_t)mtile * 256 * 1024;
    const u16* Wb = W + (size_t)ntile * 256 * 1024;

    // staging: slab = 2048 chunks (16B) per matrix; thread stages 4 chunks of A and B.
    // linear LDS dest (required by global_load_lds), inverse-swizzled global source.
    int goff[4], loff[4];
    #pragma unroll
    for (int jj = 0; jj < 4; ++jj) {
        const int q = jj * 512 + tid;            // chunk id 0..2047
        const int r = q >> 3;                    // row 0..255
        goff[jj] = r * 1024 + ((q & 7) ^ (r & 7)) * 8;
        loff[jj] = q * 8;
    }
    auto stage = [&](int pb, int kt) {
        #pragma unroll
        for (int jj = 0; jj < 4; ++jj) {
            gload_lds16(Ab + goff[jj] + kt * 64, &sA[pb][loff[jj]]);
            gload_lds16(Wb + goff[jj] + kt * 64, &sB[pb][loff[jj]]);
        }
    };

    f32x4 acc[8][4] = {};
    const int rl = lane & 15;                    // row-within-16
    const int kq = lane >> 4;                    // k-quarter 0..3
    const int sw = lane & 7;                     // swizzle key

    stage(0, 0);
    for (int t = 0; t < 16; ++t) {
        const int p = t & 1;
        asm volatile("s_waitcnt vmcnt(0)" ::: "memory");   // slab t (issued last iter) landed
        __builtin_amdgcn_sched_barrier(0);
        __builtin_amdgcn_s_barrier();                      // all waves' slab-t writes visible
        __builtin_amdgcn_sched_barrier(0);
        if (t < 15) stage(p ^ 1, t + 1);                   // overwrites slab t-1's buf: readers done pre-barrier
        #pragma unroll
        for (int h = 0; h < 2; ++h) {                      // two K=32 halves per slab
            const int cs = ((h << 2) + kq) ^ sw;
            bf16x8 af[8], bfr[4];
            #pragma unroll
            for (int mi = 0; mi < 8; ++mi)
                af[mi] = *(const bf16x8*)(&sA[p][(wm * 128 + mi * 16 + rl) * 64 + cs * 8]);
            #pragma unroll
            for (int ni = 0; ni < 4; ++ni)
                bfr[ni] = *(const bf16x8*)(&sB[p][(wn * 64 + ni * 16 + rl) * 64 + cs * 8]);
            __builtin_amdgcn_s_setprio(1);
            #pragma unroll
            for (int mi = 0; mi < 8; ++mi)
                #pragma unroll
                for (int ni = 0; ni < 4; ++ni) {
                    if (MODE == 0)   // swapped operands -> D[d][m] (transposed)
                        acc[mi][ni] = __builtin_amdgcn_mfma_f32_16x16x32_bf16(bfr[ni], af[mi], acc[mi][ni], 0, 0, 0);
                    else
                        acc[mi][ni] = __builtin_amdgcn_mfma_f32_16x16x32_bf16(af[mi], bfr[ni], acc[mi][ni], 0, 0, 0);
                }
            __builtin_amdgcn_s_setprio(0);
        }
    }

    if (MODE == 1) {
        #pragma unroll
        for (int mi = 0; mi < 8; ++mi) {
            #pragma unroll
            for (int ni = 0; ni < 4; ++ni) {
                const int n = ntile * 256 + wn * 64 + ni * 16 + (lane & 15);
                #pragma unroll
                for (int j = 0; j < 4; ++j) {
                    const int m = mtile * 256 + wm * 128 + mi * 16 + (lane >> 4) * 4 + j;
                    Cout[(size_t)m * 1024 + n] = acc[mi][ni][j];
                }
            }
        }
    } else {
        const int seg = ntile >> 2;               // 0:V 1:G 2:T 3:R (block-uniform)
        #pragma unroll
        for (int ni = 0; ni < 4; ++ni) {
            #pragma unroll
            for (int j = 0; j < 4; ++j) {
                const int d = (ntile & 3) * 256 + wn * 64 + ni * 16 + (lane >> 4) * 4 + j;
                const size_t drow = (size_t)d * MTOT;
                const int mbase = mtile * 256 + wm * 128 + (lane & 15);
                #pragma unroll
                for (int mi = 0; mi < 8; ++mi) {          // mi innermost: 64B line completes in 2 instrs
                    const int m = mbase + mi * 16;
                    const float val = acc[mi][ni][j];
                    if (seg == 0) {
                        Vt[drow + m] = f2bf(val + bp[1 + d]);
                    } else if (seg == 1) {
                        Gt[drow + m] = f2bf(sigm(val));
                    } else if (seg == 2) {
                        Tt[drow + m] = f2bf(tanh_fast(val));
                    } else {
                        Rt[drow + m] = f2bf(sigm(val));
                    }
                }
            }
        }
    }
}

// ---- K3: LDS-free sequential dual cumsum over transposed planes -------------
__global__ __launch_bounds__(64) void scan_t(
    const u16* __restrict__ Vt, const u16* __restrict__ Gt,
    const u16* __restrict__ Tt, const u16* __restrict__ Rt,
    const float* __restrict__ ub, u16* __restrict__ outb,
    float* __restrict__ act_last, float* __restrict__ gho_last)
{
    const int lane = threadIdx.x;
    const int b  = blockIdx.x >> 4;
    const int d  = ((blockIdx.x & 15) << 6) + lane;
    const int bm0 = b * T_LEN;
    const size_t rbase = (size_t)d * MTOT + bm0;
    const us8* pv = (const us8*)(Vt + rbase);
    const us8* pg = (const us8*)(Gt + rbase);
    const us8* pt = (const us8*)(Tt + rbase);
    const us8* pr = (const us8*)(Rt + rbase);

    us8 cv[2], cg[2], ct_[2], cr[2];
    #pragma unroll
    for (int h = 0; h < 2; ++h) { cv[h] = pv[h]; cg[h] = pg[h]; ct_[h] = pt[h]; cr[h] = pr[h]; }

    float acc_a = 0.f;
    _Float16 acc_g = (_Float16)0.f;

    for (int c = 0; c < 256; ++c) {
        const int cn = (c < 255) ? c + 1 : c;
        us8 nv[2], ng[2], nt2[2], nr[2];
        #pragma unroll
        for (int h = 0; h < 2; ++h) {
            nv[h] = pv[cn * 2 + h]; ng[h] = pg[cn * 2 + h];
            nt2[h] = pt[cn * 2 + h]; nr[h] = pr[cn * 2 + h];
        }
        #pragma unroll
        for (int s = 0; s < 16; ++s) {
            const int h = s >> 3, e = s & 7;
            const int t = c * 16 + s;
            const float v  = bf2f(cv[h][e]);
            const float g  = bf2f(cg[h][e]);
            const float th = bf2f(ct_[h][e]);
            const float r  = bf2f(cr[h][e]);
            const float uu = ub[bm0 + t];                 // uniform -> s_load
            acc_a = fmaf(uu, v, acc_a);                   // f32 sequential cumsum
            acc_g = acc_g + (_Float16)(g * th);           // fp16 RNE sequential cumsum
            const float comb = acc_a + (float)acc_g;
            outb[(size_t)(bm0 + t) * HD + d] = f2bf(r * comb);
        }
        #pragma unroll
        for (int h = 0; h < 2; ++h) { cv[h] = nv[h]; cg[h] = ng[h]; ct_[h] = nt2[h]; cr[h] = nr[h]; }
    }
    act_last[(size_t)b * HD + d] = acc_a;
    gho_last[(size_t)b * HD + d] = (float)acc_g;
}

extern "C" void kernel_launch(void* const* d_in, const int* in_sizes, int n_in,
                              void* d_out, int out_size, void* d_ws, size_t ws_size,
                              hipStream_t stream)
{
    const float* x   = (const float*)d_in[0];
    const float* gam = (const float*)d_in[1];
    const float* bet = (const float*)d_in[2];
    const float* Wp  = (const float*)d_in[3];
    const float* bp  = (const float*)d_in[4];
    const float* Wg  = (const float*)d_in[5];
    const float* Wt  = (const float*)d_in[6];
    const float* Wr  = (const float*)d_in[7];
    const float* Wo  = (const float*)d_in[8];

    float* out0     = (float*)d_out;                       // (B,T,H) f32
    float* act_last = out0 + (size_t)MTOT * HD;            // (B,D) f32
    float* gho_last = act_last + (size_t)B_SZ * HD;        // (B,D) fp16-valued f32

    char* ws = (char*)d_ws;
    const size_t SZ = (size_t)MTOT * HD * 2;               // 64 MiB per bf16 plane
    u16* xnb  = (u16*)(ws);                                // xn bf16; later scan output
    u16* Vt   = (u16*)(ws + SZ);                           // transposed planes [d][MTOT]
    u16* Gt   = (u16*)(ws + 2 * SZ);
    u16* Tt   = (u16*)(ws + 3 * SZ);
    u16* Rt   = (u16*)(ws + 4 * SZ);
    u16* wcat = (u16*)(ws + 5 * SZ);                       // 8,388,608 B
    u16* wob  = (u16*)(ws + 5 * SZ + 8388608);             // 2,097,152 B
    float* ub = (float*)(ws + 5 * SZ + 8388608 + 2097152); // 131,072 B

    prep_weights<<<5120, 256, 0, stream>>>(Wp, Wg, Wt, Wr, Wo, wcat, wob);
    ln_kernel<<<MTOT, 256, 0, stream>>>(x, gam, bet, Wp, bp, xnb, ub);
    gemm256<0><<<dim3(128, 16), 512, 0, stream>>>(xnb, wcat, bp, Vt, Gt, Tt, Rt, nullptr);
    scan_t<<<128, 64, 0, stream>>>(Vt, Gt, Tt, Rt, ub, xnb /*out*/, act_last, gho_last);
    gemm256<1><<<dim3(128, 4), 512, 0, stream>>>(xnb, wob, bp, nullptr, nullptr, nullptr, nullptr, out0);
}

// Round 12
// 745.778 us; speedup vs baseline: 1.3325x; 1.0962x over previous
//
#include <hip/hip_runtime.h>
#include <cstdint>
#include <cstddef>

#define B_SZ 8
#define T_LEN 4096
#define HD 1024
#define MTOT (B_SZ * T_LEN)   // 32768 tokens

typedef unsigned short u16;
typedef __attribute__((ext_vector_type(8))) short bf16x8;
typedef __attribute__((ext_vector_type(8))) unsigned short us8;
typedef __attribute__((ext_vector_type(4))) float f32x4;

static __device__ __forceinline__ float bf2f(u16 u) {
    union { unsigned i; float f; } v; v.i = ((unsigned)u) << 16; return v.f;
}
static __device__ __forceinline__ u16 f2bf(float f) {
    union { float f; unsigned i; } v; v.f = f;
    unsigned r = v.i + 0x7fffu + ((v.i >> 16) & 1u);
    return (u16)(r >> 16);
}
static __device__ __forceinline__ float sigm(float x) { return 1.f / (1.f + __expf(-x)); }
static __device__ __forceinline__ float tanh_fast(float x) { return 1.f - 2.f / (1.f + __expf(2.f * x)); }

static __device__ __forceinline__ void gload_lds16(const void* g, void* l) {
    __builtin_amdgcn_global_load_lds((const __attribute__((address_space(1))) void*)g,
                                     (__attribute__((address_space(3))) void*)l, 16, 0, 0);
}

// ---- K0: weights f32 -> bf16: wcat = [v(1024); g(1024); t(1024); r(1024)], wob = Wo
__global__ __launch_bounds__(256) void prep_weights(
    const float* __restrict__ Wp, const float* __restrict__ Wg,
    const float* __restrict__ Wt, const float* __restrict__ Wr,
    const float* __restrict__ Wo, u16* __restrict__ wcat, u16* __restrict__ wob)
{
    int i = blockIdx.x * 256 + threadIdx.x;   // float4 index
    const int T1 = 4096 * 256;
    const int T2 = 1024 * 256;
    if (i < T1) {
        int r = i >> 8, kq = i & 255;
        float4 v;
        if      (r < 1024)  v = ((const float4*)Wp)[(size_t)(r + 1) * 256 + kq];   // v-rows: Wp[1..1024]
        else if (r < 2048)  v = ((const float4*)Wg)[(size_t)(r - 1024) * 256 + kq];
        else if (r < 3072)  v = ((const float4*)Wt)[(size_t)(r - 2048) * 256 + kq];
        else                v = ((const float4*)Wr)[(size_t)(r - 3072) * 256 + kq];
        ushort4 o; o.x = f2bf(v.x); o.y = f2bf(v.y); o.z = f2bf(v.z); o.w = f2bf(v.w);
        ((ushort4*)wcat)[i] = o;
    } else if (i < T1 + T2) {
        int j = i - T1;
        float4 v = ((const float4*)Wo)[j];
        ushort4 o; o.x = f2bf(v.x); o.y = f2bf(v.y); o.z = f2bf(v.z); o.w = f2bf(v.w);
        ((ushort4*)wob)[j] = o;
    }
}

// ---- K1: LayerNorm (f32) -> xn bf16, fused u[m] = xn_f32 . Wp[0] + bp[0] ----
__global__ __launch_bounds__(256) void ln_kernel(
    const float* __restrict__ x, const float* __restrict__ gamma,
    const float* __restrict__ beta, const float* __restrict__ Wp,
    const float* __restrict__ bp, u16* __restrict__ xnb, float* __restrict__ u)
{
    __shared__ float red[8];
    const int row = blockIdx.x, tid = threadIdx.x;
    const float4 v = ((const float4*)(x + (size_t)row * HD))[tid];
    float s  = v.x + v.y + v.z + v.w;
    float sq = v.x * v.x + v.y * v.y + v.z * v.z + v.w * v.w;
    #pragma unroll
    for (int off = 32; off > 0; off >>= 1) {
        s  += __shfl_down(s, off);
        sq += __shfl_down(sq, off);
    }
    if ((tid & 63) == 0) { red[tid >> 6] = s; red[4 + (tid >> 6)] = sq; }
    __syncthreads();
    const float S   = red[0] + red[1] + red[2] + red[3];
    const float SQ  = red[4] + red[5] + red[6] + red[7];
    const float mu  = S * (1.f / HD);
    const float var = SQ * (1.f / HD) - mu * mu;
    const float rs  = rsqrtf(var + 1e-5f);
    const float4 gg = ((const float4*)gamma)[tid];
    const float4 bb = ((const float4*)beta)[tid];
    const float x0 = (v.x - mu) * rs * gg.x + bb.x;
    const float x1 = (v.y - mu) * rs * gg.y + bb.y;
    const float x2 = (v.z - mu) * rs * gg.z + bb.z;
    const float x3 = (v.w - mu) * rs * gg.w + bb.w;
    ushort4 o; o.x = f2bf(x0); o.y = f2bf(x1); o.z = f2bf(x2); o.w = f2bf(x3);
    ((ushort4*)(xnb + (size_t)row * HD))[tid] = o;
    const float4 w0 = ((const float4*)Wp)[tid];
    float su = x0 * w0.x + x1 * w0.y + x2 * w0.z + x3 * w0.w;
    #pragma unroll
    for (int off = 32; off > 0; off >>= 1) su += __shfl_down(su, off);
    __syncthreads();
    if ((tid & 63) == 0) red[tid >> 6] = su;
    __syncthreads();
    if (tid == 0) u[row] = red[0] + red[1] + red[2] + red[3] + bp[0];
}

// ---- K2/K4: bf16 MFMA GEMM, 256x256 tile, 8 waves (2M x 4N), BK=64,
// 8-phase counted-vmcnt schedule (T3+T4), double-buffered 128 KiB LDS.
// Phase = C-quadrant (m-group x K-half): {4/8 ds_read + 0-2 half-tile stages;
// fenced s_barrier; lgkmcnt(0); setprio(1); 16 MFMA; setprio(0); barrier}.
// Stage map (iter i; halves are 128-row x 64-col, 2 gloads/thread each):
//   ph0: A-h0(2i+1)->buf1   ph1: A-h1(2i+1)->buf1   ph2: -
//   ph3: B-h0(2i+2)->buf0 [gate vmcnt(2)]
//   ph4: B-h1(2i+2)+A-h0(2i+2)->buf0    ph5: A-h1(2i+2)->buf0   ph6: -
//   ph7: B-h0+h1(2i+3)->buf1 [gate vmcnt(4)]
// Retirement: buf0-B last read ph2, buf0-A ph3, buf1-B ph6, buf1-A ph7 —
// every stage is post-retirement; gates drain exactly the tiles the next
// fresh-read phase needs (counts derived in journal). Never vmcnt(0) in-loop.
// LDS swizzle as r11 (verified 0 conflicts).
// MODE 0: swapped-operand MFMA -> transposed bf16 planes [d][MTOT].
// MODE 1: normal orientation, f32 [m][1024] store.
template<int MODE>
__global__ __launch_bounds__(512) void gemm256(
    const u16* __restrict__ A, const u16* __restrict__ W,
    const float* __restrict__ bp,
    u16* __restrict__ Vt, u16* __restrict__ Gt, u16* __restrict__ Tt, u16* __restrict__ Rt,
    float* __restrict__ Cout)
{
    __shared__ u16 sA[2][256 * 64];   // 64 KiB
    __shared__ u16 sB[2][256 * 64];   // 64 KiB
    const int mtile = blockIdx.x, ntile = blockIdx.y;
    const int tid = threadIdx.x;
    const int lane = tid & 63, wave = tid >> 6;
    const int wm = wave >> 2, wn = wave & 3;     // 2M x 4N wave grid
    const u16* Ab = A + (size_t)mtile * 256 * 1024;
    const u16* Wb = W + (size_t)ntile * 256 * 1024;

    // staging precompute: half-tile = 1024 chunks; thread does chunks tid, tid+512
    const int cg = (tid & 7) ^ ((tid >> 3) & 7);         // swizzled k-chunk
    int goffj[2];
    #pragma unroll
    for (int jj = 0; jj < 2; ++jj)
        goffj[jj] = (jj * 64 + (tid >> 3)) * 1024 + cg * 8;

    auto stgA = [&](int pb, int hh, int kt) {
        const u16* src = Ab + (size_t)hh * 131072 + kt * 64;
        u16* dst = &sA[pb][hh * 8192];
        #pragma unroll
        for (int jj = 0; jj < 2; ++jj)
            gload_lds16(src + goffj[jj], dst + (jj * 512 + tid) * 8);
    };
    auto stgB = [&](int pb, int hh, int kt) {
        const u16* src = Wb + (size_t)hh * 131072 + kt * 64;
        u16* dst = &sB[pb][hh * 8192];
        #pragma unroll
        for (int jj = 0; jj < 2; ++jj)
            gload_lds16(src + goffj[jj], dst + (jj * 512 + tid) * 8);
    };

    f32x4 acc[8][4] = {};
    bf16x8 aR[4], bR[4];
    const int rl = lane & 15;
    const int kq = lane >> 4;
    const int sw = lane & 7;

    auto rdA = [&](int pb, int mg, int h) {              // aR <- 4 reads
        const int cs = ((h << 2) + kq) ^ sw;
        #pragma unroll
        for (int mi = 0; mi < 4; ++mi)
            aR[mi] = *(const bf16x8*)(&sA[pb][(wm * 128 + (mg * 4 + mi) * 16 + rl) * 64 + cs * 8]);
    };
    auto rdB = [&](int pb, int h) {                      // bR <- 4 reads
        const int cs = ((h << 2) + kq) ^ sw;
        #pragma unroll
        for (int ni = 0; ni < 4; ++ni)
            bR[ni] = *(const bf16x8*)(&sB[pb][(wn * 64 + ni * 16 + rl) * 64 + cs * 8]);
    };
    auto preMFMA = [&]() {
        __builtin_amdgcn_sched_barrier(0);
        __builtin_amdgcn_s_barrier();
        asm volatile("s_waitcnt lgkmcnt(0)" ::: "memory");
        __builtin_amdgcn_sched_barrier(0);
        __builtin_amdgcn_s_setprio(1);
    };
    auto mfma16 = [&](int mg) {
        #pragma unroll
        for (int mi = 0; mi < 4; ++mi)
            #pragma unroll
            for (int ni = 0; ni < 4; ++ni) {
                if (MODE == 0)
                    acc[mg * 4 + mi][ni] = __builtin_amdgcn_mfma_f32_16x16x32_bf16(bR[ni], aR[mi], acc[mg * 4 + mi][ni], 0, 0, 0);
                else
                    acc[mg * 4 + mi][ni] = __builtin_amdgcn_mfma_f32_16x16x32_bf16(aR[mi], bR[ni], acc[mg * 4 + mi][ni], 0, 0, 0);
            }
    };
    auto post = [&]() {                                  // no gate
        __builtin_amdgcn_s_setprio(0);
        __builtin_amdgcn_sched_barrier(0);
        __builtin_amdgcn_s_barrier();
    };
    auto postG2 = [&]() {                                // gate vmcnt(2)
        __builtin_amdgcn_s_setprio(0);
        __builtin_amdgcn_sched_barrier(0);
        asm volatile("s_waitcnt vmcnt(2)" ::: "memory");
        __builtin_amdgcn_sched_barrier(0);
        __builtin_amdgcn_s_barrier();
    };
    auto postG4 = [&]() {                                // gate vmcnt(4)
        __builtin_amdgcn_s_setprio(0);
        __builtin_amdgcn_sched_barrier(0);
        asm volatile("s_waitcnt vmcnt(4)" ::: "memory");
        __builtin_amdgcn_sched_barrier(0);
        __builtin_amdgcn_s_barrier();
    };

    // prologue: slab0 (A,B) -> buf0; B(slab1) -> buf1; drain slab0, keep B(1) flying
    stgA(0, 0, 0); stgA(0, 1, 0); stgB(0, 0, 0); stgB(0, 1, 0);
    stgB(1, 0, 1); stgB(1, 1, 1);
    asm volatile("s_waitcnt vmcnt(4)" ::: "memory");
    __builtin_amdgcn_sched_barrier(0);
    __builtin_amdgcn_s_barrier();

    for (int i = 0; i < 8; ++i) {
        const int s1 = 2 * i + 1;                        // always <= 15
        const int s2 = (2 * i + 2 < 16) ? 2 * i + 2 : 15; // clamped dead-stage in tail
        const int s3 = (2 * i + 3 < 16) ? 2 * i + 3 : 15;
        // ---- slab 2i from buf0 ----
        rdA(0, 0, 0); rdB(0, 0); stgA(1, 0, s1); preMFMA(); mfma16(0); post();
        rdA(0, 1, 0);            stgA(1, 1, s1); preMFMA(); mfma16(1); post();
        rdA(0, 0, 1); rdB(0, 1);                 preMFMA(); mfma16(0); post();
        rdA(0, 1, 1);            stgB(0, 0, s2); preMFMA(); mfma16(1); postG2();
        // ---- slab 2i+1 from buf1 ----
        rdA(1, 0, 0); rdB(1, 0); stgB(0, 1, s2);
                                 stgA(0, 0, s2); preMFMA(); mfma16(0); post();
        rdA(1, 1, 0);            stgA(0, 1, s2); preMFMA(); mfma16(1); post();
        rdA(1, 0, 1); rdB(1, 1);                 preMFMA(); mfma16(0); post();
        rdA(1, 1, 1);            stgB(1, 0, s3);
                                 stgB(1, 1, s3); preMFMA(); mfma16(1); postG4();
    }
    asm volatile("s_waitcnt vmcnt(0)" ::: "memory");     // retire tail dead-stages

    if (MODE == 1) {
        #pragma unroll
        for (int mi = 0; mi < 8; ++mi) {
            #pragma unroll
            for (int ni = 0; ni < 4; ++ni) {
                const int n = ntile * 256 + wn * 64 + ni * 16 + (lane & 15);
                #pragma unroll
                for (int j = 0; j < 4; ++j) {
                    const int m = mtile * 256 + wm * 128 + mi * 16 + (lane >> 4) * 4 + j;
                    Cout[(size_t)m * 1024 + n] = acc[mi][ni][j];
                }
            }
        }
    } else {
        const int seg = ntile >> 2;               // 0:V 1:G 2:T 3:R (block-uniform)
        #pragma unroll
        for (int ni = 0; ni < 4; ++ni) {
            #pragma unroll
            for (int j = 0; j < 4; ++j) {
                const int d = (ntile & 3) * 256 + wn * 64 + ni * 16 + (lane >> 4) * 4 + j;
                const size_t drow = (size_t)d * MTOT;
                const int mbase = mtile * 256 + wm * 128 + (lane & 15);
                #pragma unroll
                for (int mi = 0; mi < 8; ++mi) {          // mi innermost: 64B line in 2 instrs
                    const int m = mbase + mi * 16;
                    const float val = acc[mi][ni][j];
                    if (seg == 0) {
                        Vt[drow + m] = f2bf(val + bp[1 + d]);
                    } else if (seg == 1) {
                        Gt[drow + m] = f2bf(sigm(val));
                    } else if (seg == 2) {
                        Tt[drow + m] = f2bf(tanh_fast(val));
                    } else {
                        Rt[drow + m] = f2bf(sigm(val));
                    }
                }
            }
        }
    }
}

// ---- K3: LDS-free sequential dual cumsum over transposed planes -------------
__global__ __launch_bounds__(64) void scan_t(
    const u16* __restrict__ Vt, const u16* __restrict__ Gt,
    const u16* __restrict__ Tt, const u16* __restrict__ Rt,
    const float* __restrict__ ub, u16* __restrict__ outb,
    float* __restrict__ act_last, float* __restrict__ gho_last)
{
    const int lane = threadIdx.x;
    const int b  = blockIdx.x >> 4;
    const int d  = ((blockIdx.x & 15) << 6) + lane;
    const int bm0 = b * T_LEN;
    const size_t rbase = (size_t)d * MTOT + bm0;
    const us8* pv = (const us8*)(Vt + rbase);
    const us8* pg = (const us8*)(Gt + rbase);
    const us8* pt = (const us8*)(Tt + rbase);
    const us8* pr = (const us8*)(Rt + rbase);

    us8 cv[2], cg[2], ct_[2], cr[2];
    #pragma unroll
    for (int h = 0; h < 2; ++h) { cv[h] = pv[h]; cg[h] = pg[h]; ct_[h] = pt[h]; cr[h] = pr[h]; }

    float acc_a = 0.f;
    _Float16 acc_g = (_Float16)0.f;

    for (int c = 0; c < 256; ++c) {
        const int cn = (c < 255) ? c + 1 : c;
        us8 nv[2], ng[2], nt2[2], nr[2];
        #pragma unroll
        for (int h = 0; h < 2; ++h) {
            nv[h] = pv[cn * 2 + h]; ng[h] = pg[cn * 2 + h];
            nt2[h] = pt[cn * 2 + h]; nr[h] = pr[cn * 2 + h];
        }
        #pragma unroll
        for (int s = 0; s < 16; ++s) {
            const int h = s >> 3, e = s & 7;
            const int t = c * 16 + s;
            const float v  = bf2f(cv[h][e]);
            const float g  = bf2f(cg[h][e]);
            const float th = bf2f(ct_[h][e]);
            const float r  = bf2f(cr[h][e]);
            const float uu = ub[bm0 + t];                 // uniform -> s_load
            acc_a = fmaf(uu, v, acc_a);                   // f32 sequential cumsum
            acc_g = acc_g + (_Float16)(g * th);           // fp16 RNE sequential cumsum
            const float comb = acc_a + (float)acc_g;
            outb[(size_t)(bm0 + t) * HD + d] = f2bf(r * comb);
        }
        #pragma unroll
        for (int h = 0; h < 2; ++h) { cv[h] = nv[h]; cg[h] = ng[h]; ct_[h] = nt2[h]; cr[h] = nr[h]; }
    }
    act_last[(size_t)b * HD + d] = acc_a;
    gho_last[(size_t)b * HD + d] = (float)acc_g;
}

extern "C" void kernel_launch(void* const* d_in, const int* in_sizes, int n_in,
                              void* d_out, int out_size, void* d_ws, size_t ws_size,
                              hipStream_t stream)
{
    const float* x   = (const float*)d_in[0];
    const float* gam = (const float*)d_in[1];
    const float* bet = (const float*)d_in[2];
    const float* Wp  = (const float*)d_in[3];
    const float* bp  = (const float*)d_in[4];
    const float* Wg  = (const float*)d_in[5];
    const float* Wt  = (const float*)d_in[6];
    const float* Wr  = (const float*)d_in[7];
    const float* Wo  = (const float*)d_in[8];

    float* out0     = (float*)d_out;                       // (B,T,H) f32
    float* act_last = out0 + (size_t)MTOT * HD;            // (B,D) f32
    float* gho_last = act_last + (size_t)B_SZ * HD;        // (B,D) fp16-valued f32

    char* ws = (char*)d_ws;
    const size_t SZ = (size_t)MTOT * HD * 2;               // 64 MiB per bf16 plane
    u16* xnb  = (u16*)(ws);                                // xn bf16; later scan output
    u16* Vt   = (u16*)(ws + SZ);                           // transposed planes [d][MTOT]
    u16* Gt   = (u16*)(ws + 2 * SZ);
    u16* Tt   = (u16*)(ws + 3 * SZ);
    u16* Rt   = (u16*)(ws + 4 * SZ);
    u16* wcat = (u16*)(ws + 5 * SZ);                       // 8,388,608 B
    u16* wob  = (u16*)(ws + 5 * SZ + 8388608);             // 2,097,152 B
    float* ub = (float*)(ws + 5 * SZ + 8388608 + 2097152); // 131,072 B

    prep_weights<<<5120, 256, 0, stream>>>(Wp, Wg, Wt, Wr, Wo, wcat, wob);
    ln_kernel<<<MTOT, 256, 0, stream>>>(x, gam, bet, Wp, bp, xnb, ub);
    gemm256<0><<<dim3(128, 16), 512, 0, stream>>>(xnb, wcat, bp, Vt, Gt, Tt, Rt, nullptr);
    scan_t<<<128, 64, 0, stream>>>(Vt, Gt, Tt, Rt, ub, xnb /*out*/, act_last, gho_last);
    gemm256<1><<<dim3(128, 4), 512, 0, stream>>>(xnb, wob, bp, nullptr, nullptr, nullptr, nullptr, out0);
}

// Round 13
// 729.780 us; speedup vs baseline: 1.3617x; 1.0219x over previous
//
#include <hip/hip_runtime.h>
#include <cstdint>
#include <cstddef>

#define B_SZ 8
#define T_LEN 4096
#define HD 1024
#define MTOT (B_SZ * T_LEN)   // 32768 tokens

typedef unsigned short u16;
typedef __attribute__((ext_vector_type(8))) short bf16x8;
typedef __attribute__((ext_vector_type(8))) unsigned short us8;
typedef __attribute__((ext_vector_type(4))) float f32x4;

static __device__ __forceinline__ float bf2f(u16 u) {
    union { unsigned i; float f; } v; v.i = ((unsigned)u) << 16; return v.f;
}
static __device__ __forceinline__ u16 f2bf(float f) {
    union { float f; unsigned i; } v; v.f = f;
    unsigned r = v.i + 0x7fffu + ((v.i >> 16) & 1u);
    return (u16)(r >> 16);
}
static __device__ __forceinline__ float sigm(float x) { return 1.f / (1.f + __expf(-x)); }
static __device__ __forceinline__ float tanh_fast(float x) { return 1.f - 2.f / (1.f + __expf(2.f * x)); }

static __device__ __forceinline__ void gload_lds16(const void* g, void* l) {
    __builtin_amdgcn_global_load_lds((const __attribute__((address_space(1))) void*)g,
                                     (__attribute__((address_space(3))) void*)l, 16, 0, 0);
}

// ---- K0: weights f32 -> bf16: wcat = [v(1024); g(1024); t(1024); r(1024)], wob = Wo
__global__ __launch_bounds__(256) void prep_weights(
    const float* __restrict__ Wp, const float* __restrict__ Wg,
    const float* __restrict__ Wt, const float* __restrict__ Wr,
    const float* __restrict__ Wo, u16* __restrict__ wcat, u16* __restrict__ wob)
{
    int i = blockIdx.x * 256 + threadIdx.x;   // float4 index
    const int T1 = 4096 * 256;
    const int T2 = 1024 * 256;
    if (i < T1) {
        int r = i >> 8, kq = i & 255;
        float4 v;
        if      (r < 1024)  v = ((const float4*)Wp)[(size_t)(r + 1) * 256 + kq];   // v-rows: Wp[1..1024]
        else if (r < 2048)  v = ((const float4*)Wg)[(size_t)(r - 1024) * 256 + kq];
        else if (r < 3072)  v = ((const float4*)Wt)[(size_t)(r - 2048) * 256 + kq];
        else                v = ((const float4*)Wr)[(size_t)(r - 3072) * 256 + kq];
        ushort4 o; o.x = f2bf(v.x); o.y = f2bf(v.y); o.z = f2bf(v.z); o.w = f2bf(v.w);
        ((ushort4*)wcat)[i] = o;
    } else if (i < T1 + T2) {
        int j = i - T1;
        float4 v = ((const float4*)Wo)[j];
        ushort4 o; o.x = f2bf(v.x); o.y = f2bf(v.y); o.z = f2bf(v.z); o.w = f2bf(v.w);
        ((ushort4*)wob)[j] = o;
    }
}

// ---- K1: LayerNorm (f32) -> xn bf16, fused u[m] = xn_f32 . Wp[0] + bp[0] ----
__global__ __launch_bounds__(256) void ln_kernel(
    const float* __restrict__ x, const float* __restrict__ gamma,
    const float* __restrict__ beta, const float* __restrict__ Wp,
    const float* __restrict__ bp, u16* __restrict__ xnb, float* __restrict__ u)
{
    __shared__ float red[8];
    const int row = blockIdx.x, tid = threadIdx.x;
    const float4 v = ((const float4*)(x + (size_t)row * HD))[tid];
    float s  = v.x + v.y + v.z + v.w;
    float sq = v.x * v.x + v.y * v.y + v.z * v.z + v.w * v.w;
    #pragma unroll
    for (int off = 32; off > 0; off >>= 1) {
        s  += __shfl_down(s, off);
        sq += __shfl_down(sq, off);
    }
    if ((tid & 63) == 0) { red[tid >> 6] = s; red[4 + (tid >> 6)] = sq; }
    __syncthreads();
    const float S   = red[0] + red[1] + red[2] + red[3];
    const float SQ  = red[4] + red[5] + red[6] + red[7];
    const float mu  = S * (1.f / HD);
    const float var = SQ * (1.f / HD) - mu * mu;
    const float rs  = rsqrtf(var + 1e-5f);
    const float4 gg = ((const float4*)gamma)[tid];
    const float4 bb = ((const float4*)beta)[tid];
    const float x0 = (v.x - mu) * rs * gg.x + bb.x;
    const float x1 = (v.y - mu) * rs * gg.y + bb.y;
    const float x2 = (v.z - mu) * rs * gg.z + bb.z;
    const float x3 = (v.w - mu) * rs * gg.w + bb.w;
    ushort4 o; o.x = f2bf(x0); o.y = f2bf(x1); o.z = f2bf(x2); o.w = f2bf(x3);
    ((ushort4*)(xnb + (size_t)row * HD))[tid] = o;
    const float4 w0 = ((const float4*)Wp)[tid];
    float su = x0 * w0.x + x1 * w0.y + x2 * w0.z + x3 * w0.w;
    #pragma unroll
    for (int off = 32; off > 0; off >>= 1) su += __shfl_down(su, off);
    __syncthreads();
    if ((tid & 63) == 0) red[tid >> 6] = su;
    __syncthreads();
    if (tid == 0) u[row] = red[0] + red[1] + red[2] + red[3] + bp[0];
}

// ---- K2/K4: bf16 MFMA GEMM, 256x256 tile, **16 waves** (4M x 4N, 64x64/wave),
// BK=64, double-buffered 128 KiB LDS, round-8-verified single-barrier skeleton:
//   { vmcnt(0); SB; s_barrier; SB; stage slab t+1 -> buf p^1; 2x(8 ds_read + 16 MFMA) }
// acc = 4x4 f32x4 = 64 regs -> total <=128 unified regs/wave -> 16 waves/CU
// (4 waves/SIMD: reads and MFMAs of staggered waves interleave on each SIMD).
// LDS swizzle as r11 (verified 0 conflicts): store cg = cs ^ (r&7);
// read cs = (h*4 + (lane>>4)) ^ (lane&7)  [frag rows 16-aligned].
// MODE 0: swapped-operand MFMA -> transposed bf16 planes [d][MTOT], mi-inner stores.
// MODE 1: normal orientation, f32 [m][1024] store.
template<int MODE>
__global__ __launch_bounds__(1024, 4) void gemm256(
    const u16* __restrict__ A, const u16* __restrict__ W,
    const float* __restrict__ bp,
    u16* __restrict__ Vt, u16* __restrict__ Gt, u16* __restrict__ Tt, u16* __restrict__ Rt,
    float* __restrict__ Cout)
{
    __shared__ u16 sA[2][256 * 64];   // 64 KiB
    __shared__ u16 sB[2][256 * 64];   // 64 KiB
    const int mtile = blockIdx.x, ntile = blockIdx.y;
    const int tid = threadIdx.x;
    const int lane = tid & 63, wave = tid >> 6;
    const int wm = wave >> 2, wn = wave & 3;     // 4M x 4N wave grid, 64x64 per wave
    const u16* Ab = A + (size_t)mtile * 256 * 1024;
    const u16* Wb = W + (size_t)ntile * 256 * 1024;

    // staging: slab = 2048 chunks (16B) per matrix; thread stages 2 chunks of A and B.
    // linear LDS dest (required by global_load_lds), inverse-swizzled global source.
    int goff[2], loff[2];
    #pragma unroll
    for (int jj = 0; jj < 2; ++jj) {
        const int q = jj * 1024 + tid;           // chunk id 0..2047
        const int r = q >> 3;                    // row 0..255
        goff[jj] = r * 1024 + ((q & 7) ^ (r & 7)) * 8;
        loff[jj] = q * 8;
    }
    auto stage = [&](int pb, int kt) {
        #pragma unroll
        for (int jj = 0; jj < 2; ++jj) {
            gload_lds16(Ab + goff[jj] + kt * 64, &sA[pb][loff[jj]]);
            gload_lds16(Wb + goff[jj] + kt * 64, &sB[pb][loff[jj]]);
        }
    };

    f32x4 acc[4][4] = {};
    const int rl = lane & 15;                    // row-within-16
    const int kq = lane >> 4;                    // k-quarter 0..3
    const int sw = lane & 7;                     // swizzle key
    const int abase = (wm * 64 + rl) * 64;       // u16 units
    const int bbase = (wn * 64 + rl) * 64;

    stage(0, 0);
    for (int t = 0; t < 16; ++t) {
        const int p = t & 1;
        asm volatile("s_waitcnt vmcnt(0)" ::: "memory");   // slab t (issued last iter) landed
        __builtin_amdgcn_sched_barrier(0);
        __builtin_amdgcn_s_barrier();                      // all waves' slab-t writes visible
        __builtin_amdgcn_sched_barrier(0);
        if (t < 15) stage(p ^ 1, t + 1);                   // overwrites slab t-1's buf: readers done pre-barrier
        #pragma unroll
        for (int h = 0; h < 2; ++h) {                      // two K=32 halves per slab
            const int cs = ((h << 2) + kq) ^ sw;
            bf16x8 af[4], bfr[4];
            #pragma unroll
            for (int mi = 0; mi < 4; ++mi)
                af[mi] = *(const bf16x8*)(&sA[p][abase + mi * 1024 + cs * 8]);
            #pragma unroll
            for (int ni = 0; ni < 4; ++ni)
                bfr[ni] = *(const bf16x8*)(&sB[p][bbase + ni * 1024 + cs * 8]);
            __builtin_amdgcn_s_setprio(1);
            #pragma unroll
            for (int mi = 0; mi < 4; ++mi)
                #pragma unroll
                for (int ni = 0; ni < 4; ++ni) {
                    if (MODE == 0)   // swapped operands -> D[d][m] (transposed)
                        acc[mi][ni] = __builtin_amdgcn_mfma_f32_16x16x32_bf16(bfr[ni], af[mi], acc[mi][ni], 0, 0, 0);
                    else
                        acc[mi][ni] = __builtin_amdgcn_mfma_f32_16x16x32_bf16(af[mi], bfr[ni], acc[mi][ni], 0, 0, 0);
                }
            __builtin_amdgcn_s_setprio(0);
        }
    }

    if (MODE == 1) {
        #pragma unroll
        for (int mi = 0; mi < 4; ++mi) {
            #pragma unroll
            for (int ni = 0; ni < 4; ++ni) {
                const int n = ntile * 256 + wn * 64 + ni * 16 + (lane & 15);
                #pragma unroll
                for (int j = 0; j < 4; ++j) {
                    const int m = mtile * 256 + wm * 64 + mi * 16 + (lane >> 4) * 4 + j;
                    Cout[(size_t)m * 1024 + n] = acc[mi][ni][j];
                }
            }
        }
    } else {
        const int seg = ntile >> 2;               // 0:V 1:G 2:T 3:R (block-uniform)
        #pragma unroll
        for (int ni = 0; ni < 4; ++ni) {
            #pragma unroll
            for (int j = 0; j < 4; ++j) {
                const int d = (ntile & 3) * 256 + wn * 64 + ni * 16 + (lane >> 4) * 4 + j;
                const size_t drow = (size_t)d * MTOT;
                const int mbase = mtile * 256 + wm * 64 + (lane & 15);
                #pragma unroll
                for (int mi = 0; mi < 4; ++mi) {          // mi innermost: 64B line completes fast
                    const int m = mbase + mi * 16;
                    const float val = acc[mi][ni][j];
                    if (seg == 0) {
                        Vt[drow + m] = f2bf(val + bp[1 + d]);
                    } else if (seg == 1) {
                        Gt[drow + m] = f2bf(sigm(val));
                    } else if (seg == 2) {
                        Tt[drow + m] = f2bf(tanh_fast(val));
                    } else {
                        Rt[drow + m] = f2bf(sigm(val));
                    }
                }
            }
        }
    }
}

// ---- K3: LDS-free sequential dual cumsum over transposed planes -------------
__global__ __launch_bounds__(64) void scan_t(
    const u16* __restrict__ Vt, const u16* __restrict__ Gt,
    const u16* __restrict__ Tt, const u16* __restrict__ Rt,
    const float* __restrict__ ub, u16* __restrict__ outb,
    float* __restrict__ act_last, float* __restrict__ gho_last)
{
    const int lane = threadIdx.x;
    const int b  = blockIdx.x >> 4;
    const int d  = ((blockIdx.x & 15) << 6) + lane;
    const int bm0 = b * T_LEN;
    const size_t rbase = (size_t)d * MTOT + bm0;
    const us8* pv = (const us8*)(Vt + rbase);
    const us8* pg = (const us8*)(Gt + rbase);
    const us8* pt = (const us8*)(Tt + rbase);
    const us8* pr = (const us8*)(Rt + rbase);

    us8 cv[2], cg[2], ct_[2], cr[2];
    #pragma unroll
    for (int h = 0; h < 2; ++h) { cv[h] = pv[h]; cg[h] = pg[h]; ct_[h] = pt[h]; cr[h] = pr[h]; }

    float acc_a = 0.f;
    _Float16 acc_g = (_Float16)0.f;

    for (int c = 0; c < 256; ++c) {
        const int cn = (c < 255) ? c + 1 : c;
        us8 nv[2], ng[2], nt2[2], nr[2];
        #pragma unroll
        for (int h = 0; h < 2; ++h) {
            nv[h] = pv[cn * 2 + h]; ng[h] = pg[cn * 2 + h];
            nt2[h] = pt[cn * 2 + h]; nr[h] = pr[cn * 2 + h];
        }
        #pragma unroll
        for (int s = 0; s < 16; ++s) {
            const int h = s >> 3, e = s & 7;
            const int t = c * 16 + s;
            const float v  = bf2f(cv[h][e]);
            const float g  = bf2f(cg[h][e]);
            const float th = bf2f(ct_[h][e]);
            const float r  = bf2f(cr[h][e]);
            const float uu = ub[bm0 + t];                 // uniform -> s_load
            acc_a = fmaf(uu, v, acc_a);                   // f32 sequential cumsum
            acc_g = acc_g + (_Float16)(g * th);           // fp16 RNE sequential cumsum
            const float comb = acc_a + (float)acc_g;
            outb[(size_t)(bm0 + t) * HD + d] = f2bf(r * comb);
        }
        #pragma unroll
        for (int h = 0; h < 2; ++h) { cv[h] = nv[h]; cg[h] = ng[h]; ct_[h] = nt2[h]; cr[h] = nr[h]; }
    }
    act_last[(size_t)b * HD + d] = acc_a;
    gho_last[(size_t)b * HD + d] = (float)acc_g;
}

extern "C" void kernel_launch(void* const* d_in, const int* in_sizes, int n_in,
                              void* d_out, int out_size, void* d_ws, size_t ws_size,
                              hipStream_t stream)
{
    const float* x   = (const float*)d_in[0];
    const float* gam = (const float*)d_in[1];
    const float* bet = (const float*)d_in[2];
    const float* Wp  = (const float*)d_in[3];
    const float* bp  = (const float*)d_in[4];
    const float* Wg  = (const float*)d_in[5];
    const float* Wt  = (const float*)d_in[6];
    const float* Wr  = (const float*)d_in[7];
    const float* Wo  = (const float*)d_in[8];

    float* out0     = (float*)d_out;                       // (B,T,H) f32
    float* act_last = out0 + (size_t)MTOT * HD;            // (B,D) f32
    float* gho_last = act_last + (size_t)B_SZ * HD;        // (B,D) fp16-valued f32

    char* ws = (char*)d_ws;
    const size_t SZ = (size_t)MTOT * HD * 2;               // 64 MiB per bf16 plane
    u16* xnb  = (u16*)(ws);                                // xn bf16; later scan output
    u16* Vt   = (u16*)(ws + SZ);                           // transposed planes [d][MTOT]
    u16* Gt   = (u16*)(ws + 2 * SZ);
    u16* Tt   = (u16*)(ws + 3 * SZ);
    u16* Rt   = (u16*)(ws + 4 * SZ);
    u16* wcat = (u16*)(ws + 5 * SZ);                       // 8,388,608 B
    u16* wob  = (u16*)(ws + 5 * SZ + 8388608);             // 2,097,152 B
    float* ub = (float*)(ws + 5 * SZ + 8388608 + 2097152); // 131,072 B

    prep_weights<<<5120, 256, 0, stream>>>(Wp, Wg, Wt, Wr, Wo, wcat, wob);
    ln_kernel<<<MTOT, 256, 0, stream>>>(x, gam, bet, Wp, bp, xnb, ub);
    gemm256<0><<<dim3(128, 16), 1024, 0, stream>>>(xnb, wcat, bp, Vt, Gt, Tt, Rt, nullptr);
    scan_t<<<128, 64, 0, stream>>>(Vt, Gt, Tt, Rt, ub, xnb /*out*/, act_last, gho_last);
    gemm256<1><<<dim3(128, 4), 1024, 0, stream>>>(xnb, wob, bp, nullptr, nullptr, nullptr, nullptr, out0);
}

// Round 14
// 669.973 us; speedup vs baseline: 1.4832x; 1.0893x over previous
//
#include <hip/hip_runtime.h>
#include <cstdint>
#include <cstddef>

#define B_SZ 8
#define T_LEN 4096
#define HD 1024
#define MTOT (B_SZ * T_LEN)   // 32768 tokens

typedef unsigned short u16;
typedef __attribute__((ext_vector_type(8))) short bf16x8;
typedef __attribute__((ext_vector_type(8))) unsigned short us8;
typedef __attribute__((ext_vector_type(4))) float f32x4;

static __device__ __forceinline__ float bf2f(u16 u) {
    union { unsigned i; float f; } v; v.i = ((unsigned)u) << 16; return v.f;
}
static __device__ __forceinline__ u16 f2bf(float f) {
    union { float f; unsigned i; } v; v.f = f;
    unsigned r = v.i + 0x7fffu + ((v.i >> 16) & 1u);
    return (u16)(r >> 16);
}
static __device__ __forceinline__ float sigm(float x) { return 1.f / (1.f + __expf(-x)); }
static __device__ __forceinline__ float tanh_fast(float x) { return 1.f - 2.f / (1.f + __expf(2.f * x)); }
static __device__ __forceinline__ float f4get(const float4& f, int k) {
    return k == 0 ? f.x : k == 1 ? f.y : k == 2 ? f.z : f.w;   // k static post-unroll
}

static __device__ __forceinline__ void gload_lds16(const void* g, void* l) {
    __builtin_amdgcn_global_load_lds((const __attribute__((address_space(1))) void*)g,
                                     (__attribute__((address_space(3))) void*)l, 16, 0, 0);
}

// ---- K0: weights f32 -> bf16: wcat = [v(1024); g(1024); t(1024); r(1024)], wob = Wo
__global__ __launch_bounds__(256) void prep_weights(
    const float* __restrict__ Wp, const float* __restrict__ Wg,
    const float* __restrict__ Wt, const float* __restrict__ Wr,
    const float* __restrict__ Wo, u16* __restrict__ wcat, u16* __restrict__ wob)
{
    int i = blockIdx.x * 256 + threadIdx.x;   // float4 index
    const int T1 = 4096 * 256;
    const int T2 = 1024 * 256;
    if (i < T1) {
        int r = i >> 8, kq = i & 255;
        float4 v;
        if      (r < 1024)  v = ((const float4*)Wp)[(size_t)(r + 1) * 256 + kq];   // v-rows: Wp[1..1024]
        else if (r < 2048)  v = ((const float4*)Wg)[(size_t)(r - 1024) * 256 + kq];
        else if (r < 3072)  v = ((const float4*)Wt)[(size_t)(r - 2048) * 256 + kq];
        else                v = ((const float4*)Wr)[(size_t)(r - 3072) * 256 + kq];
        ushort4 o; o.x = f2bf(v.x); o.y = f2bf(v.y); o.z = f2bf(v.z); o.w = f2bf(v.w);
        ((ushort4*)wcat)[i] = o;
    } else if (i < T1 + T2) {
        int j = i - T1;
        float4 v = ((const float4*)Wo)[j];
        ushort4 o; o.x = f2bf(v.x); o.y = f2bf(v.y); o.z = f2bf(v.z); o.w = f2bf(v.w);
        ((ushort4*)wob)[j] = o;
    }
}

// ---- K1: LayerNorm (f32) -> xn bf16, fused u[m] = xn_f32 . Wp[0] + bp[0] ----
__global__ __launch_bounds__(256) void ln_kernel(
    const float* __restrict__ x, const float* __restrict__ gamma,
    const float* __restrict__ beta, const float* __restrict__ Wp,
    const float* __restrict__ bp, u16* __restrict__ xnb, float* __restrict__ u)
{
    __shared__ float red[8];
    const int row = blockIdx.x, tid = threadIdx.x;
    const float4 v = ((const float4*)(x + (size_t)row * HD))[tid];
    float s  = v.x + v.y + v.z + v.w;
    float sq = v.x * v.x + v.y * v.y + v.z * v.z + v.w * v.w;
    #pragma unroll
    for (int off = 32; off > 0; off >>= 1) {
        s  += __shfl_down(s, off);
        sq += __shfl_down(sq, off);
    }
    if ((tid & 63) == 0) { red[tid >> 6] = s; red[4 + (tid >> 6)] = sq; }
    __syncthreads();
    const float S   = red[0] + red[1] + red[2] + red[3];
    const float SQ  = red[4] + red[5] + red[6] + red[7];
    const float mu  = S * (1.f / HD);
    const float var = SQ * (1.f / HD) - mu * mu;
    const float rs  = rsqrtf(var + 1e-5f);
    const float4 gg = ((const float4*)gamma)[tid];
    const float4 bb = ((const float4*)beta)[tid];
    const float x0 = (v.x - mu) * rs * gg.x + bb.x;
    const float x1 = (v.y - mu) * rs * gg.y + bb.y;
    const float x2 = (v.z - mu) * rs * gg.z + bb.z;
    const float x3 = (v.w - mu) * rs * gg.w + bb.w;
    ushort4 o; o.x = f2bf(x0); o.y = f2bf(x1); o.z = f2bf(x2); o.w = f2bf(x3);
    ((ushort4*)(xnb + (size_t)row * HD))[tid] = o;
    const float4 w0 = ((const float4*)Wp)[tid];
    float su = x0 * w0.x + x1 * w0.y + x2 * w0.z + x3 * w0.w;
    #pragma unroll
    for (int off = 32; off > 0; off >>= 1) su += __shfl_down(su, off);
    __syncthreads();
    if ((tid & 63) == 0) red[tid >> 6] = su;
    __syncthreads();
    if (tid == 0) u[row] = red[0] + red[1] + red[2] + red[3] + bp[0];
}

// ---- K2/K4: bf16 MFMA GEMM, 256x256 tile, 16 waves (4M x 4N, 64x64/wave),
// BK=64, dbuf 128 KiB LDS, single-barrier pipelined K-loop (r13-verified), with
// minimal fencing: { vmcnt(0); s_barrier; sched_barrier(0); stage(t+1); compute(t) }
// — compiler free to interleave stage issue / ds_reads / MFMAs within the slab.
// LDS swizzle (verified 0 conflicts): store cg = cs ^ (r&7);
// read cs = (h*4 + (lane>>4)) ^ (lane&7)  [frag rows 16-aligned].
// MODE 0: swapped-operand MFMA -> transposed bf16 planes [d][MTOT], mi-inner stores.
// MODE 1: normal orientation, f32 [m][1024] store.
template<int MODE>
__global__ __launch_bounds__(1024, 4) void gemm256(
    const u16* __restrict__ A, const u16* __restrict__ W,
    const float* __restrict__ bp,
    u16* __restrict__ Vt, u16* __restrict__ Gt, u16* __restrict__ Tt, u16* __restrict__ Rt,
    float* __restrict__ Cout)
{
    __shared__ u16 sA[2][256 * 64];   // 64 KiB
    __shared__ u16 sB[2][256 * 64];   // 64 KiB
    const int mtile = blockIdx.x, ntile = blockIdx.y;
    const int tid = threadIdx.x;
    const int lane = tid & 63, wave = tid >> 6;
    const int wm = wave >> 2, wn = wave & 3;     // 4M x 4N wave grid, 64x64 per wave
    const u16* Ab = A + (size_t)mtile * 256 * 1024;
    const u16* Wb = W + (size_t)ntile * 256 * 1024;

    // staging: slab = 2048 chunks (16B) per matrix; thread stages 2 chunks of A and B.
    int goff[2], loff[2];
    #pragma unroll
    for (int jj = 0; jj < 2; ++jj) {
        const int q = jj * 1024 + tid;           // chunk id 0..2047
        const int r = q >> 3;                    // row 0..255
        goff[jj] = r * 1024 + ((q & 7) ^ (r & 7)) * 8;
        loff[jj] = q * 8;
    }
    auto stage = [&](int pb, int kt) {
        #pragma unroll
        for (int jj = 0; jj < 2; ++jj) {
            gload_lds16(Ab + goff[jj] + kt * 64, &sA[pb][loff[jj]]);
            gload_lds16(Wb + goff[jj] + kt * 64, &sB[pb][loff[jj]]);
        }
    };

    f32x4 acc[4][4] = {};
    const int rl = lane & 15;                    // row-within-16
    const int kq = lane >> 4;                    // k-quarter 0..3
    const int sw = lane & 7;                     // swizzle key
    const int abase = (wm * 64 + rl) * 64;       // u16 units
    const int bbase = (wn * 64 + rl) * 64;

    stage(0, 0);
    for (int t = 0; t < 16; ++t) {
        const int p = t & 1;
        asm volatile("s_waitcnt vmcnt(0)" ::: "memory");   // slab t (issued last iter) landed
        __builtin_amdgcn_s_barrier();                      // all waves' slab-t writes visible
        __builtin_amdgcn_sched_barrier(0);                 // nothing below crosses above barrier
        if (t < 15) stage(p ^ 1, t + 1);                   // overwrites slab t-1's buf: readers done pre-barrier
        #pragma unroll
        for (int h = 0; h < 2; ++h) {                      // two K=32 halves per slab
            const int cs = ((h << 2) + kq) ^ sw;
            bf16x8 af[4], bfr[4];
            #pragma unroll
            for (int mi = 0; mi < 4; ++mi)
                af[mi] = *(const bf16x8*)(&sA[p][abase + mi * 1024 + cs * 8]);
            #pragma unroll
            for (int ni = 0; ni < 4; ++ni)
                bfr[ni] = *(const bf16x8*)(&sB[p][bbase + ni * 1024 + cs * 8]);
            __builtin_amdgcn_s_setprio(1);
            #pragma unroll
            for (int mi = 0; mi < 4; ++mi)
                #pragma unroll
                for (int ni = 0; ni < 4; ++ni) {
                    if (MODE == 0)   // swapped operands -> D[d][m] (transposed)
                        acc[mi][ni] = __builtin_amdgcn_mfma_f32_16x16x32_bf16(bfr[ni], af[mi], acc[mi][ni], 0, 0, 0);
                    else
                        acc[mi][ni] = __builtin_amdgcn_mfma_f32_16x16x32_bf16(af[mi], bfr[ni], acc[mi][ni], 0, 0, 0);
                }
            __builtin_amdgcn_s_setprio(0);
        }
    }

    if (MODE == 1) {
        #pragma unroll
        for (int mi = 0; mi < 4; ++mi) {
            #pragma unroll
            for (int ni = 0; ni < 4; ++ni) {
                const int n = ntile * 256 + wn * 64 + ni * 16 + (lane & 15);
                #pragma unroll
                for (int j = 0; j < 4; ++j) {
                    const int m = mtile * 256 + wm * 64 + mi * 16 + (lane >> 4) * 4 + j;
                    Cout[(size_t)m * 1024 + n] = acc[mi][ni][j];
                }
            }
        }
    } else {
        const int seg = ntile >> 2;               // 0:V 1:G 2:T 3:R (block-uniform)
        #pragma unroll
        for (int ni = 0; ni < 4; ++ni) {
            #pragma unroll
            for (int j = 0; j < 4; ++j) {
                const int d = (ntile & 3) * 256 + wn * 64 + ni * 16 + (lane >> 4) * 4 + j;
                const size_t drow = (size_t)d * MTOT;
                const int mbase = mtile * 256 + wm * 64 + (lane & 15);
                #pragma unroll
                for (int mi = 0; mi < 4; ++mi) {          // mi innermost: 64B line completes fast
                    const int m = mbase + mi * 16;
                    const float val = acc[mi][ni][j];
                    if (seg == 0) {
                        Vt[drow + m] = f2bf(val + bp[1 + d]);
                    } else if (seg == 1) {
                        Gt[drow + m] = f2bf(sigm(val));
                    } else if (seg == 2) {
                        Tt[drow + m] = f2bf(tanh_fast(val));
                    } else {
                        Rt[drow + m] = f2bf(sigm(val));
                    }
                }
            }
        }
    }
}

// ---- K3: LDS-free sequential dual cumsum, depth-3 register prefetch ---------
// 128 blocks x 64 threads; lane owns one (b,d) chain. 4-slot rotation (statically
// indexed after unroll), 3 chunks (3x128B/lane) in flight -> BW-saturating.
__global__ __launch_bounds__(64) void scan_t(
    const u16* __restrict__ Vt, const u16* __restrict__ Gt,
    const u16* __restrict__ Tt, const u16* __restrict__ Rt,
    const float* __restrict__ ub, u16* __restrict__ outb,
    float* __restrict__ act_last, float* __restrict__ gho_last)
{
    const int lane = threadIdx.x;
    const int b  = blockIdx.x >> 4;
    const int d  = ((blockIdx.x & 15) << 6) + lane;
    const int bm0 = b * T_LEN;
    const size_t rbase = (size_t)d * MTOT + bm0;
    const us8* pv = (const us8*)(Vt + rbase);
    const us8* pg = (const us8*)(Gt + rbase);
    const us8* pt = (const us8*)(Tt + rbase);
    const us8* pr = (const us8*)(Rt + rbase);
    const float4* pu = (const float4*)(ub + bm0);   // lane-uniform -> scalar loads

    us8 sv[4][2], sg[4][2], st[4][2], sr[4][2];
    float4 su[4][4];

    #pragma unroll
    for (int c = 0; c < 3; ++c) {
        #pragma unroll
        for (int h = 0; h < 2; ++h) {
            sv[c][h] = pv[c * 2 + h]; sg[c][h] = pg[c * 2 + h];
            st[c][h] = pt[c * 2 + h]; sr[c][h] = pr[c * 2 + h];
        }
        #pragma unroll
        for (int q = 0; q < 4; ++q) su[c][q] = pu[c * 4 + q];
    }

    float acc_a = 0.f;
    _Float16 acc_g = (_Float16)0.f;

    for (int cq = 0; cq < 64; ++cq) {
        #pragma unroll
        for (int s = 0; s < 4; ++s) {                       // slot indices static
            const int c = cq * 4 + s;
            const int cn = c + 3;
            const int sl = (s + 3) & 3;
            if (cn < 256) {
                #pragma unroll
                for (int h = 0; h < 2; ++h) {
                    sv[sl][h] = pv[cn * 2 + h]; sg[sl][h] = pg[cn * 2 + h];
                    st[sl][h] = pt[cn * 2 + h]; sr[sl][h] = pr[cn * 2 + h];
                }
                #pragma unroll
                for (int q = 0; q < 4; ++q) su[sl][q] = pu[cn * 4 + q];
            }
            #pragma unroll
            for (int e16 = 0; e16 < 16; ++e16) {
                const int h = e16 >> 3, e = e16 & 7;
                const float v  = bf2f(sv[s][h][e]);
                const float g  = bf2f(sg[s][h][e]);
                const float th = bf2f(st[s][h][e]);
                const float r  = bf2f(sr[s][h][e]);
                const float uu = f4get(su[s][e16 >> 2], e16 & 3);
                acc_a = fmaf(uu, v, acc_a);                 // f32 sequential cumsum
                acc_g = acc_g + (_Float16)(g * th);         // fp16 RNE sequential cumsum
                const float comb = acc_a + (float)acc_g;
                outb[(size_t)(bm0 + c * 16 + e16) * HD + d] = f2bf(r * comb);
            }
        }
    }
    act_last[(size_t)b * HD + d] = acc_a;
    gho_last[(size_t)b * HD + d] = (float)acc_g;
}

extern "C" void kernel_launch(void* const* d_in, const int* in_sizes, int n_in,
                              void* d_out, int out_size, void* d_ws, size_t ws_size,
                              hipStream_t stream)
{
    const float* x   = (const float*)d_in[0];
    const float* gam = (const float*)d_in[1];
    const float* bet = (const float*)d_in[2];
    const float* Wp  = (const float*)d_in[3];
    const float* bp  = (const float*)d_in[4];
    const float* Wg  = (const float*)d_in[5];
    const float* Wt  = (const float*)d_in[6];
    const float* Wr  = (const float*)d_in[7];
    const float* Wo  = (const float*)d_in[8];

    float* out0     = (float*)d_out;                       // (B,T,H) f32
    float* act_last = out0 + (size_t)MTOT * HD;            // (B,D) f32
    float* gho_last = act_last + (size_t)B_SZ * HD;        // (B,D) fp16-valued f32

    char* ws = (char*)d_ws;
    const size_t SZ = (size_t)MTOT * HD * 2;               // 64 MiB per bf16 plane
    u16* xnb  = (u16*)(ws);                                // xn bf16; later scan output
    u16* Vt   = (u16*)(ws + SZ);                           // transposed planes [d][MTOT]
    u16* Gt   = (u16*)(ws + 2 * SZ);
    u16* Tt   = (u16*)(ws + 3 * SZ);
    u16* Rt   = (u16*)(ws + 4 * SZ);
    u16* wcat = (u16*)(ws + 5 * SZ);                       // 8,388,608 B
    u16* wob  = (u16*)(ws + 5 * SZ + 8388608);             // 2,097,152 B
    float* ub = (float*)(ws + 5 * SZ + 8388608 + 2097152); // 131,072 B

    prep_weights<<<5120, 256, 0, stream>>>(Wp, Wg, Wt, Wr, Wo, wcat, wob);
    ln_kernel<<<MTOT, 256, 0, stream>>>(x, gam, bet, Wp, bp, xnb, ub);
    gemm256<0><<<dim3(128, 16), 1024, 0, stream>>>(xnb, wcat, bp, Vt, Gt, Tt, Rt, nullptr);
    scan_t<<<128, 64, 0, stream>>>(Vt, Gt, Tt, Rt, ub, xnb /*out*/, act_last, gho_last);
    gemm256<1><<<dim3(128, 4), 1024, 0, stream>>>(xnb, wob, bp, nullptr, nullptr, nullptr, nullptr, out0);
}

// Round 15
// 657.209 us; speedup vs baseline: 1.5120x; 1.0194x over previous
//
#include <hip/hip_runtime.h>
#include <cstdint>
#include <cstddef>

#define B_SZ 8
#define T_LEN 4096
#define HD 1024
#define MTOT (B_SZ * T_LEN)   // 32768 tokens

typedef unsigned short u16;
typedef __attribute__((ext_vector_type(8))) short bf16x8;
typedef __attribute__((ext_vector_type(8))) unsigned short us8;
typedef __attribute__((ext_vector_type(4))) float f32x4;
typedef __attribute__((ext_vector_type(16))) float f32x16;

static __device__ __forceinline__ float bf2f(u16 u) {
    union { unsigned i; float f; } v; v.i = ((unsigned)u) << 16; return v.f;
}
static __device__ __forceinline__ u16 f2bf(float f) {
    union { float f; unsigned i; } v; v.f = f;
    unsigned r = v.i + 0x7fffu + ((v.i >> 16) & 1u);
    return (u16)(r >> 16);
}
static __device__ __forceinline__ float sigm(float x) { return 1.f / (1.f + __expf(-x)); }
static __device__ __forceinline__ float tanh_fast(float x) { return 1.f - 2.f / (1.f + __expf(2.f * x)); }
static __device__ __forceinline__ float f4get(const float4& f, int k) {
    return k == 0 ? f.x : k == 1 ? f.y : k == 2 ? f.z : f.w;   // k static post-unroll
}

static __device__ __forceinline__ void gload_lds16(const void* g, void* l) {
    __builtin_amdgcn_global_load_lds((const __attribute__((address_space(1))) void*)g,
                                     (__attribute__((address_space(3))) void*)l, 16, 0, 0);
}

// ---- K0: weights f32 -> bf16: wcat = [v(1024); g(1024); t(1024); r(1024)], wob = Wo
__global__ __launch_bounds__(256) void prep_weights(
    const float* __restrict__ Wp, const float* __restrict__ Wg,
    const float* __restrict__ Wt, const float* __restrict__ Wr,
    const float* __restrict__ Wo, u16* __restrict__ wcat, u16* __restrict__ wob)
{
    int i = blockIdx.x * 256 + threadIdx.x;   // float4 index
    const int T1 = 4096 * 256;
    const int T2 = 1024 * 256;
    if (i < T1) {
        int r = i >> 8, kq = i & 255;
        float4 v;
        if      (r < 1024)  v = ((const float4*)Wp)[(size_t)(r + 1) * 256 + kq];   // v-rows: Wp[1..1024]
        else if (r < 2048)  v = ((const float4*)Wg)[(size_t)(r - 1024) * 256 + kq];
        else if (r < 3072)  v = ((const float4*)Wt)[(size_t)(r - 2048) * 256 + kq];
        else                v = ((const float4*)Wr)[(size_t)(r - 3072) * 256 + kq];
        ushort4 o; o.x = f2bf(v.x); o.y = f2bf(v.y); o.z = f2bf(v.z); o.w = f2bf(v.w);
        ((ushort4*)wcat)[i] = o;
    } else if (i < T1 + T2) {
        int j = i - T1;
        float4 v = ((const float4*)Wo)[j];
        ushort4 o; o.x = f2bf(v.x); o.y = f2bf(v.y); o.z = f2bf(v.z); o.w = f2bf(v.w);
        ((ushort4*)wob)[j] = o;
    }
}

// ---- K1: LayerNorm (f32) -> xn bf16, fused u[m] = xn_f32 . Wp[0] + bp[0] ----
__global__ __launch_bounds__(256) void ln_kernel(
    const float* __restrict__ x, const float* __restrict__ gamma,
    const float* __restrict__ beta, const float* __restrict__ Wp,
    const float* __restrict__ bp, u16* __restrict__ xnb, float* __restrict__ u)
{
    __shared__ float red[8];
    const int row = blockIdx.x, tid = threadIdx.x;
    const float4 v = ((const float4*)(x + (size_t)row * HD))[tid];
    float s  = v.x + v.y + v.z + v.w;
    float sq = v.x * v.x + v.y * v.y + v.z * v.z + v.w * v.w;
    #pragma unroll
    for (int off = 32; off > 0; off >>= 1) {
        s  += __shfl_down(s, off);
        sq += __shfl_down(sq, off);
    }
    if ((tid & 63) == 0) { red[tid >> 6] = s; red[4 + (tid >> 6)] = sq; }
    __syncthreads();
    const float S   = red[0] + red[1] + red[2] + red[3];
    const float SQ  = red[4] + red[5] + red[6] + red[7];
    const float mu  = S * (1.f / HD);
    const float var = SQ * (1.f / HD) - mu * mu;
    const float rs  = rsqrtf(var + 1e-5f);
    const float4 gg = ((const float4*)gamma)[tid];
    const float4 bb = ((const float4*)beta)[tid];
    const float x0 = (v.x - mu) * rs * gg.x + bb.x;
    const float x1 = (v.y - mu) * rs * gg.y + bb.y;
    const float x2 = (v.z - mu) * rs * gg.z + bb.z;
    const float x3 = (v.w - mu) * rs * gg.w + bb.w;
    ushort4 o; o.x = f2bf(x0); o.y = f2bf(x1); o.z = f2bf(x2); o.w = f2bf(x3);
    ((ushort4*)(xnb + (size_t)row * HD))[tid] = o;
    const float4 w0 = ((const float4*)Wp)[tid];
    float su = x0 * w0.x + x1 * w0.y + x2 * w0.z + x3 * w0.w;
    #pragma unroll
    for (int off = 32; off > 0; off >>= 1) su += __shfl_down(su, off);
    __syncthreads();
    if ((tid & 63) == 0) red[tid >> 6] = su;
    __syncthreads();
    if (tid == 0) u[row] = red[0] + red[1] + red[2] + red[3] + bp[0];
}

// ---- K2/K4: bf16 MFMA GEMM, 256x256 tile, 16 waves (4M x 4N, 64x64/wave),
// BK=64, dbuf 128 KiB LDS, r14-verified single-barrier pipelined K-loop.
// NEW (r15): 32x32x16 MFMA (4060 FLOP/cyc vs 3377 for 16x16x32; half the
// MFMA instructions). Wave tile = 2x2 frags of 32x32; acc[2][2] f32x16 = 64 regs.
// Operand map (mirrors verified 16x16 convention): row = lane&31,
// k = (lane>>5)*8 + e. C/D (doc-verified m74/m101): col = lane&31,
// row = (r&3) + 8*(r>>2) + 4*(lane>>5), r in [0,16).
// LDS swizzle (verified 0 conflicts): store cg = cs ^ (row&7);
// read cs = (ks*2 + (lane>>5)) ^ (lane&7)  [frag rows 32-aligned].
// MODE 0: swapped-operand MFMA -> transposed bf16 planes [d][MTOT]
//         (each store = two complete 64B lines). MODE 1: f32 [m][1024] store.
template<int MODE>
__global__ __launch_bounds__(1024, 4) void gemm256(
    const u16* __restrict__ A, const u16* __restrict__ W,
    const float* __restrict__ bp,
    u16* __restrict__ Vt, u16* __restrict__ Gt, u16* __restrict__ Tt, u16* __restrict__ Rt,
    float* __restrict__ Cout)
{
    __shared__ u16 sA[2][256 * 64];   // 64 KiB
    __shared__ u16 sB[2][256 * 64];   // 64 KiB
    const int mtile = blockIdx.x, ntile = blockIdx.y;
    const int tid = threadIdx.x;
    const int lane = tid & 63, wave = tid >> 6;
    const int wm = wave >> 2, wn = wave & 3;     // 4M x 4N wave grid, 64x64 per wave
    const u16* Ab = A + (size_t)mtile * 256 * 1024;
    const u16* Wb = W + (size_t)ntile * 256 * 1024;

    // staging: slab = 2048 chunks (16B) per matrix; thread stages 2 chunks of A and B.
    int goff[2], loff[2];
    #pragma unroll
    for (int jj = 0; jj < 2; ++jj) {
        const int q = jj * 1024 + tid;           // chunk id 0..2047
        const int r = q >> 3;                    // row 0..255
        goff[jj] = r * 1024 + ((q & 7) ^ (r & 7)) * 8;
        loff[jj] = q * 8;
    }
    auto stage = [&](int pb, int kt) {
        #pragma unroll
        for (int jj = 0; jj < 2; ++jj) {
            gload_lds16(Ab + goff[jj] + kt * 64, &sA[pb][loff[jj]]);
            gload_lds16(Wb + goff[jj] + kt * 64, &sB[pb][loff[jj]]);
        }
    };

    f32x16 acc[2][2] = {};
    const int rl32  = lane & 31;                 // row-within-32
    const int khalf = lane >> 5;                 // k-half 0/1
    const int sw    = lane & 7;                  // swizzle key
    const int abase = (wm * 64 + rl32) * 64;     // u16 units
    const int bbase = (wn * 64 + rl32) * 64;

    stage(0, 0);
    for (int t = 0; t < 16; ++t) {
        const int p = t & 1;
        asm volatile("s_waitcnt vmcnt(0)" ::: "memory");   // slab t (issued last iter) landed
        __builtin_amdgcn_s_barrier();                      // all waves' slab-t writes visible
        __builtin_amdgcn_sched_barrier(0);                 // nothing below crosses above barrier
        if (t < 15) stage(p ^ 1, t + 1);                   // overwrites slab t-1's buf: readers done pre-barrier
        #pragma unroll
        for (int ks = 0; ks < 4; ++ks) {                   // four K=16 steps per slab
            const int cs = (ks * 2 + khalf) ^ sw;
            bf16x8 aR[2], bR[2];
            #pragma unroll
            for (int sm = 0; sm < 2; ++sm)
                aR[sm] = *(const bf16x8*)(&sA[p][abase + sm * 2048 + cs * 8]);
            #pragma unroll
            for (int sn = 0; sn < 2; ++sn)
                bR[sn] = *(const bf16x8*)(&sB[p][bbase + sn * 2048 + cs * 8]);
            __builtin_amdgcn_s_setprio(1);
            #pragma unroll
            for (int sm = 0; sm < 2; ++sm)
                #pragma unroll
                for (int sn = 0; sn < 2; ++sn) {
                    if (MODE == 0)   // swapped operands -> D[d][m] (transposed)
                        acc[sm][sn] = __builtin_amdgcn_mfma_f32_32x32x16_bf16(bR[sn], aR[sm], acc[sm][sn], 0, 0, 0);
                    else
                        acc[sm][sn] = __builtin_amdgcn_mfma_f32_32x32x16_bf16(aR[sm], bR[sn], acc[sm][sn], 0, 0, 0);
                }
            __builtin_amdgcn_s_setprio(0);
        }
    }

    if (MODE == 1) {
        #pragma unroll
        for (int sm = 0; sm < 2; ++sm) {
            #pragma unroll
            for (int sn = 0; sn < 2; ++sn) {
                const int n = ntile * 256 + wn * 64 + sn * 32 + rl32;
                #pragma unroll
                for (int r = 0; r < 16; ++r) {
                    const int m = mtile * 256 + wm * 64 + sm * 32 + (r & 3) + 8 * (r >> 2) + 4 * khalf;
                    Cout[(size_t)m * 1024 + n] = acc[sm][sn][r];
                }
            }
        }
    } else {
        const int seg = ntile >> 2;               // 0:V 1:G 2:T 3:R (block-uniform)
        #pragma unroll
        for (int sn = 0; sn < 2; ++sn) {
            #pragma unroll
            for (int r = 0; r < 16; ++r) {
                const int d = (ntile & 3) * 256 + wn * 64 + sn * 32 + (r & 3) + 8 * (r >> 2) + 4 * khalf;
                const size_t drow = (size_t)d * MTOT;
                #pragma unroll
                for (int sm = 0; sm < 2; ++sm) {          // two complete 64B lines per store
                    const int m = mtile * 256 + wm * 64 + sm * 32 + rl32;
                    const float val = acc[sm][sn][r];
                    if (seg == 0) {
                        Vt[drow + m] = f2bf(val + bp[1 + d]);
                    } else if (seg == 1) {
                        Gt[drow + m] = f2bf(sigm(val));
                    } else if (seg == 2) {
                        Tt[drow + m] = f2bf(tanh_fast(val));
                    } else {
                        Rt[drow + m] = f2bf(sigm(val));
                    }
                }
            }
        }
    }
}

// ---- K3: LDS-free sequential dual cumsum, depth-3 register prefetch ---------
__global__ __launch_bounds__(64) void scan_t(
    const u16* __restrict__ Vt, const u16* __restrict__ Gt,
    const u16* __restrict__ Tt, const u16* __restrict__ Rt,
    const float* __restrict__ ub, u16* __restrict__ outb,
    float* __restrict__ act_last, float* __restrict__ gho_last)
{
    const int lane = threadIdx.x;
    const int b  = blockIdx.x >> 4;
    const int d  = ((blockIdx.x & 15) << 6) + lane;
    const int bm0 = b * T_LEN;
    const size_t rbase = (size_t)d * MTOT + bm0;
    const us8* pv = (const us8*)(Vt + rbase);
    const us8* pg = (const us8*)(Gt + rbase);
    const us8* pt = (const us8*)(Tt + rbase);
    const us8* pr = (const us8*)(Rt + rbase);
    const float4* pu = (const float4*)(ub + bm0);   // lane-uniform -> scalar loads

    us8 sv[4][2], sg[4][2], st[4][2], sr[4][2];
    float4 su[4][4];

    #pragma unroll
    for (int c = 0; c < 3; ++c) {
        #pragma unroll
        for (int h = 0; h < 2; ++h) {
            sv[c][h] = pv[c * 2 + h]; sg[c][h] = pg[c * 2 + h];
            st[c][h] = pt[c * 2 + h]; sr[c][h] = pr[c * 2 + h];
        }
        #pragma unroll
        for (int q = 0; q < 4; ++q) su[c][q] = pu[c * 4 + q];
    }

    float acc_a = 0.f;
    _Float16 acc_g = (_Float16)0.f;

    for (int cq = 0; cq < 64; ++cq) {
        #pragma unroll
        for (int s = 0; s < 4; ++s) {                       // slot indices static
            const int c = cq * 4 + s;
            const int cn = c + 3;
            const int sl = (s + 3) & 3;
            if (cn < 256) {
                #pragma unroll
                for (int h = 0; h < 2; ++h) {
                    sv[sl][h] = pv[cn * 2 + h]; sg[sl][h] = pg[cn * 2 + h];
                    st[sl][h] = pt[cn * 2 + h]; sr[sl][h] = pr[cn * 2 + h];
                }
                #pragma unroll
                for (int q = 0; q < 4; ++q) su[sl][q] = pu[cn * 4 + q];
            }
            #pragma unroll
            for (int e16 = 0; e16 < 16; ++e16) {
                const int h = e16 >> 3, e = e16 & 7;
                const float v  = bf2f(sv[s][h][e]);
                const float g  = bf2f(sg[s][h][e]);
                const float th = bf2f(st[s][h][e]);
                const float r  = bf2f(sr[s][h][e]);
                const float uu = f4get(su[s][e16 >> 2], e16 & 3);
                acc_a = fmaf(uu, v, acc_a);                 // f32 sequential cumsum
                acc_g = acc_g + (_Float16)(g * th);         // fp16 RNE sequential cumsum
                const float comb = acc_a + (float)acc_g;
                outb[(size_t)(bm0 + c * 16 + e16) * HD + d] = f2bf(r * comb);
            }
        }
    }
    act_last[(size_t)b * HD + d] = acc_a;
    gho_last[(size_t)b * HD + d] = (float)acc_g;
}

extern "C" void kernel_launch(void* const* d_in, const int* in_sizes, int n_in,
                              void* d_out, int out_size, void* d_ws, size_t ws_size,
                              hipStream_t stream)
{
    const float* x   = (const float*)d_in[0];
    const float* gam = (const float*)d_in[1];
    const float* bet = (const float*)d_in[2];
    const float* Wp  = (const float*)d_in[3];
    const float* bp  = (const float*)d_in[4];
    const float* Wg  = (const float*)d_in[5];
    const float* Wt  = (const float*)d_in[6];
    const float* Wr  = (const float*)d_in[7];
    const float* Wo  = (const float*)d_in[8];

    float* out0     = (float*)d_out;                       // (B,T,H) f32
    float* act_last = out0 + (size_t)MTOT * HD;            // (B,D) f32
    float* gho_last = act_last + (size_t)B_SZ * HD;        // (B,D) fp16-valued f32

    char* ws = (char*)d_ws;
    const size_t SZ = (size_t)MTOT * HD * 2;               // 64 MiB per bf16 plane
    u16* xnb  = (u16*)(ws);                                // xn bf16; later scan output
    u16* Vt   = (u16*)(ws + SZ);                           // transposed planes [d][MTOT]
    u16* Gt   = (u16*)(ws + 2 * SZ);
    u16* Tt   = (u16*)(ws + 3 * SZ);
    u16* Rt   = (u16*)(ws + 4 * SZ);
    u16* wcat = (u16*)(ws + 5 * SZ);                       // 8,388,608 B
    u16* wob  = (u16*)(ws + 5 * SZ + 8388608);             // 2,097,152 B
    float* ub = (float*)(ws + 5 * SZ + 8388608 + 2097152); // 131,072 B

    prep_weights<<<5120, 256, 0, stream>>>(Wp, Wg, Wt, Wr, Wo, wcat, wob);
    ln_kernel<<<MTOT, 256, 0, stream>>>(x, gam, bet, Wp, bp, xnb, ub);
    gemm256<0><<<dim3(128, 16), 1024, 0, stream>>>(xnb, wcat, bp, Vt, Gt, Tt, Rt, nullptr);
    scan_t<<<128, 64, 0, stream>>>(Vt, Gt, Tt, Rt, ub, xnb /*out*/, act_last, gho_last);
    gemm256<1><<<dim3(128, 4), 1024, 0, stream>>>(xnb, wob, bp, nullptr, nullptr, nullptr, nullptr, out0);
}